// Round 7
// baseline (880.679 us; speedup 1.0000x reference)
//
#include <hip/hip_runtime.h>

// SCAESuite R7: entry-major pipelined scatter + 2-pass bf16 radix + 512-thr fixups.
// n=1024 tokens, D=768, F=8192, K=64, C=128. Inputs f32, output f32.
//  - gemm_mfma: bf16 16x16x32 MFMA, 128x128 tile -> X bf16 (selection only)
//  - vconn: 4 D-chunk launches (3MB gather set, L2-resident), writes PACKED
//    pe[p] = (fd<<16)|bf16(val)  (v_inv/pack pass eliminated)
//  - phase2sel: flattened entry range, 4-deep load pipeline, 2-pass u16 radix
//  - select_up: u16-key LDS radix (2 passes)
//  - fixup_*: 512 threads (8 waves), exact f64 rescore, bitonic top-64
//  - decode_both: single 2048-block kernel for both decodes
//  - ws ~62.7 MiB; WddT aliases [X16|B16]

#define NTOK 1024
#define DIM  768
#define FF   8192
#define KK   64
#define CC   128
#define KSEL_UP 80
#define KSEL_DN 96
#define CAP  128

typedef unsigned short u16;
typedef unsigned int   u32;
typedef __attribute__((ext_vector_type(8))) short short8;
typedef __attribute__((ext_vector_type(4))) float floatx4;

__device__ __forceinline__ float bits2f(u32 v) {
    float f; __builtin_memcpy(&f, &v, 4); return f;
}
__device__ __forceinline__ float bf2f(u16 u) { return bits2f(((u32)u) << 16); }
__device__ __forceinline__ u16 f2bf(float f) {
    u32 u; __builtin_memcpy(&u, &f, 4);
    u32 lsb = (u >> 16) & 1u;
    u += 0x7fffu + lsb;
    return (u16)(u >> 16);
}
// monotone bf16-bits -> u16 ordering key
__device__ __forceinline__ u16 bfkey(u16 b) {
    return (b & 0x8000u) ? (u16)~b : (u16)(b | 0x8000u);
}

// ---------------- f32 -> bf16 bulk convert --------------------------------------
__global__ __launch_bounds__(256) void convert_kernel(const float* __restrict__ src,
                                                      u16* __restrict__ dst, int n4) {
    int i = blockIdx.x * 256 + threadIdx.x;
    if (i < n4) {
        float4 v = ((const float4*)src)[i];
        ushort4 o;
        o.x = f2bf(v.x); o.y = f2bf(v.y); o.z = f2bf(v.z); o.w = f2bf(v.w);
        ((ushort4*)dst)[i] = o;
    }
}

// ---------------- transpose: f32 [DIM][FF] -> f32 [FF][DIM] ---------------------
__global__ __launch_bounds__(256) void transpose_kernel(const float* __restrict__ in,
                                                        float* __restrict__ out) {
    __shared__ float tile[32][33];
    int f0 = blockIdx.x * 32, d0 = blockIdx.y * 32;
    int tx = threadIdx.x, ty = threadIdx.y;
#pragma unroll
    for (int i = 0; i < 4; ++i)
        tile[ty + 8 * i][tx] = in[(size_t)(d0 + ty + 8 * i) * FF + f0 + tx];
    __syncthreads();
#pragma unroll
    for (int i = 0; i < 4; ++i)
        out[(size_t)(f0 + ty + 8 * i) * DIM + d0 + tx] = tile[tx][ty + 8 * i];
}

// ---------------- bias dots (f32 + f64 copies + c2 = bed - t_dn) ----------------
__global__ __launch_bounds__(64) void bias_kernel(const float* __restrict__ Weu,
                                                  const float* __restrict__ Wed,
                                                  const float* __restrict__ bdu,
                                                  const float* __restrict__ bdd,
                                                  const float* __restrict__ bed,
                                                  float* __restrict__ sF,
                                                  float* __restrict__ tuF,
                                                  float* __restrict__ c2F,
                                                  double* __restrict__ s64,
                                                  double* __restrict__ tu64,
                                                  double* __restrict__ td64) {
    int f = blockIdx.x, lane = threadIdx.x;
    double su = 0.0, tu = 0.0, td = 0.0;
    for (int i = lane; i < DIM; i += 64) {
        double bu = (double)bdu[i], bd = (double)bdd[i];
        su += (double)Weu[(size_t)f * DIM + i] * bu;
        double w = (double)Wed[(size_t)f * DIM + i];
        tu += w * bu;
        td += w * bd;
    }
#pragma unroll
    for (int off = 32; off; off >>= 1) {
        su += __shfl_xor(su, off);
        tu += __shfl_xor(tu, off);
        td += __shfl_xor(td, off);
    }
    if (lane == 0) {
        sF[f] = (float)su; tuF[f] = (float)tu;
        c2F[f] = (float)((double)bed[f] - td);
        s64[f] = su; tu64[f] = tu; td64[f] = td;
    }
}

// ---------------- bf16 MFMA GEMM: X[t,f] = sum_d A[t,d]*B[f,d] ------------------
template <int MODE>
__global__ __launch_bounds__(256) void gemm_mfma(const u16* __restrict__ A16,
                                                 const u16* __restrict__ B16,
                                                 u16* __restrict__ Xout,
                                                 const float* __restrict__ sF,
                                                 const float* __restrict__ b_enc) {
    __shared__ __align__(16) u16 As[128 * 40];
    __shared__ __align__(16) u16 Bs[128 * 40];
    int tid = threadIdx.x;
    int wave = tid >> 6, lane = tid & 63;
    int lm = lane & 15, quad = lane >> 4;
    int m0 = blockIdx.y * 128, n0 = blockIdx.x * 128;
    int wm = (wave >> 1) * 64, wn = (wave & 1) * 64;
    floatx4 acc[4][4];
#pragma unroll
    for (int i = 0; i < 4; ++i)
#pragma unroll
        for (int j = 0; j < 4; ++j)
            acc[i][j] = (floatx4){0.f, 0.f, 0.f, 0.f};
    int r = tid >> 2;
    int s = (tid & 3) * 8;
    const u16* gA = A16 + (size_t)(m0 + r) * DIM + s;
    const u16* gB = B16 + (size_t)(n0 + r) * DIM + s;
    for (int k0 = 0; k0 < DIM; k0 += 32) {
        __syncthreads();
        *(int4*)&As[r * 40 + s]          = *(const int4*)(gA + k0);
        *(int4*)&As[(r + 64) * 40 + s]   = *(const int4*)(gA + (size_t)64 * DIM + k0);
        *(int4*)&Bs[r * 40 + s]          = *(const int4*)(gB + k0);
        *(int4*)&Bs[(r + 64) * 40 + s]   = *(const int4*)(gB + (size_t)64 * DIM + k0);
        __syncthreads();
        short8 af[4], bfr[4];
#pragma unroll
        for (int mi = 0; mi < 4; ++mi)
            af[mi] = *(const short8*)&As[(wm + mi * 16 + lm) * 40 + quad * 8];
#pragma unroll
        for (int ni = 0; ni < 4; ++ni)
            bfr[ni] = *(const short8*)&Bs[(wn + ni * 16 + lm) * 40 + quad * 8];
#pragma unroll
        for (int mi = 0; mi < 4; ++mi)
#pragma unroll
            for (int ni = 0; ni < 4; ++ni)
                acc[mi][ni] = __builtin_amdgcn_mfma_f32_16x16x32_bf16(
                    af[mi], bfr[ni], acc[mi][ni], 0, 0, 0);
    }
#pragma unroll
    for (int ni = 0; ni < 4; ++ni) {
        int col = n0 + wn + ni * 16 + lm;
        float sub = 0.f, bb = 0.f;
        if (MODE == 0) { sub = sF[col]; bb = b_enc[col]; }
#pragma unroll
        for (int mi = 0; mi < 4; ++mi) {
#pragma unroll
            for (int reg = 0; reg < 4; ++reg) {
                int row = m0 + wm + mi * 16 + quad * 4 + reg;
                float v = acc[mi][ni][reg];
                if (MODE == 0) { v = v - sub + bb; v = v > 0.f ? v : 0.f; }
                Xout[(size_t)row * FF + col] = f2bf(v);
            }
        }
    }
}

// ---------------- shared radix-collect helper (2-pass over u16 keys in LDS) -----
// Returns via cand/cnt. keys[FF], hist[256], eqidx[256] must be provided.
__device__ void radix_collect_u16(const u16* keys, u32* hist, int* eqidx,
                                  int ksel, u16* cr, int* cnt_out, int row,
                                  u32* shG, u32* shE, int* shB, int* shK) {
    int tid = threadIdx.x;
    // pass 1: high byte
    if (tid < 256) hist[tid] = 0;
    __syncthreads();
    for (int i = tid; i < FF; i += blockDim.x) atomicAdd(&hist[keys[i] >> 8], 1u);
    __syncthreads();
    if (tid == 0) {
        int rem = ksel, b = 255;
        for (; b > 0; --b) { int h = (int)hist[b]; if (rem <= h) break; rem -= h; }
        *shB = b; *shK = rem;
    }
    __syncthreads();
    int hb = *shB;
    if (tid < 256) hist[tid] = 0;
    __syncthreads();
    for (int i = tid; i < FF; i += blockDim.x) {
        u16 k = keys[i];
        if ((int)(k >> 8) == hb) atomicAdd(&hist[k & 255u], 1u);
    }
    __syncthreads();
    if (tid == 0) {
        int rem = *shK, b = 255;
        for (; b > 0; --b) { int h = (int)hist[b]; if (rem <= h) break; rem -= h; }
        *shB = (hb << 8) | b;
        *shG = 0; *shE = 0;
    }
    __syncthreads();
    u16 T = (u16)*shB;
    for (int i = tid; i < FF; i += blockDim.x) {
        u16 k = keys[i];
        if (k > T) {
            u32 p = atomicAdd(shG, 1u);
            if (p < CAP) cr[p] = (u16)i;
        } else if (k == T) {
            u32 p = atomicAdd(shE, 1u);
            if (p < 256) eqidx[p] = i;
        }
    }
    __syncthreads();
    if (tid == 0) {
        int G = (int)*shG; if (G > CAP) G = CAP;
        int ne = (int)*shE; if (ne > 256) ne = 256;
        int total = G;
        for (int q = 0; q < ne && total < CAP; ++q) cr[total++] = (u16)eqidx[q];
        cnt_out[row] = total;
    }
}

// ---------------- select_up: u16 keys in LDS + 2-pass radix ---------------------
__global__ __launch_bounds__(256) void select_up_kernel(const u16* __restrict__ X16,
                                                        u16* __restrict__ cand,
                                                        int* __restrict__ cnt) {
    __shared__ u16 keys[FF];
    __shared__ u32 hist[256];
    __shared__ int eqidx[256];
    __shared__ u32 shG, shE;
    __shared__ int shB, shK;
    const int row = blockIdx.x, tid = threadIdx.x;
    const ushort4* src = (const ushort4*)(X16 + (size_t)row * FF);
    for (int i = tid; i < FF / 4; i += 256) {
        ushort4 u = src[i];
        keys[i * 4]     = bfkey(u.x);
        keys[i * 4 + 1] = bfkey(u.y);
        keys[i * 4 + 2] = bfkey(u.z);
        keys[i * 4 + 3] = bfkey(u.w);
    }
    __syncthreads();
    radix_collect_u16(keys, hist, eqidx, KSEL_UP, cand + (size_t)row * CAP, cnt, row,
                      &shG, &shE, &shB, &shK);
}

// ---------------- bitonic sort of 128 (desc by val, asc idx) --------------------
__device__ __forceinline__ bool sort_before(double av, int ai, double bv, int bi) {
    return (av > bv) || (av == bv && ai < bi);
}
__device__ void bitonic128(double* sv, int* si, int tid) {
    for (int k = 2; k <= 128; k <<= 1) {
        for (int j = k >> 1; j > 0; j >>= 1) {
            __syncthreads();
            if (tid < 64) {
                int i = ((tid & ~(j - 1)) << 1) | (tid & (j - 1));
                int l = i, rr = i + j;
                bool bfirst = sort_before(sv[rr], si[rr], sv[l], si[l]);
                bool doswap = ((i & k) == 0) ? bfirst : !bfirst;
                if (doswap) {
                    double tv = sv[l]; sv[l] = sv[rr]; sv[rr] = tv;
                    int ti = si[l]; si[l] = si[rr]; si[rr] = ti;
                }
            }
        }
    }
    __syncthreads();
}

// ---------------- exact rescore (up), 512 threads -------------------------------
__global__ __launch_bounds__(512) void fixup_up(const float* __restrict__ xu,
                                                const float* __restrict__ Weu,
                                                const double* __restrict__ s64,
                                                const float* __restrict__ beu,
                                                const u16* __restrict__ cand,
                                                const int* __restrict__ cnt,
                                                float* __restrict__ vals,
                                                int* __restrict__ idxs) {
    __shared__ float xrow[DIM];
    __shared__ double sv[128];
    __shared__ int si[128];
    int t = blockIdx.x, tid = threadIdx.x, wave = tid >> 6, lane = tid & 63;
    for (int i = tid; i < DIM; i += 512) xrow[i] = xu[(size_t)t * DIM + i];
    for (int c = tid; c < 128; c += 512) { sv[c] = -1.0e300; si[c] = 0x7fffffff; }
    __syncthreads();
    int nc = cnt[t]; if (nc > 128) nc = 128;
    for (int c = wave; c < nc; c += 8) {
        int f = (int)cand[(size_t)t * CAP + c];
        const float* wr = Weu + (size_t)f * DIM;
        double p = 0.0;
#pragma unroll
        for (int i = 0; i < 12; ++i) {
            int d = lane + 64 * i;
            p += (double)xrow[d] * (double)wr[d];
        }
#pragma unroll
        for (int off = 32; off; off >>= 1) p += __shfl_xor(p, off);
        if (lane == 0) {
            double v = p - s64[f] + (double)beu[f];
            v = v > 0.0 ? v : 0.0;
            sv[c] = v; si[c] = f;
        }
    }
    __syncthreads();
    bitonic128(sv, si, tid);
    if (tid < KK) {
        vals[(size_t)t * KK + tid] = (float)sv[tid];
        idxs[(size_t)t * KK + tid] = si[tid];
    }
}

// ---------------- exact rescore (down), 512 threads -----------------------------
__global__ __launch_bounds__(512) void fixup_dn(const float* __restrict__ x0,
                                                const float* __restrict__ Wed,
                                                const float* __restrict__ WduT,
                                                const double* __restrict__ tu64,
                                                const double* __restrict__ td64,
                                                const float* __restrict__ bed,
                                                const float* __restrict__ ln,
                                                const u16* __restrict__ cclean,
                                                const float* __restrict__ vals_up,
                                                const int* __restrict__ idx_up,
                                                const u16* __restrict__ cand,
                                                const int* __restrict__ cnt,
                                                float* __restrict__ vals,
                                                int* __restrict__ idxs) {
    __shared__ float xrow[DIM];
    __shared__ u32 bm[256];
    __shared__ int fl[KK];
    __shared__ float zl[KK];
    __shared__ double sv[128];
    __shared__ int si[128];
    int t = blockIdx.x, tid = threadIdx.x, wave = tid >> 6, lane = tid & 63;
    for (int i = tid; i < DIM; i += 512) xrow[i] = x0[(size_t)t * DIM + i];
    if (tid < 256) bm[tid] = 0;
    for (int c = tid; c < 128; c += 512) { sv[c] = -1.0e300; si[c] = 0x7fffffff; }
    __syncthreads();
    if (tid < KK) {
        int f = idx_up[(size_t)t * KK + tid];
        fl[tid] = f; zl[tid] = vals_up[(size_t)t * KK + tid];
        atomicOr(&bm[f >> 5], 1u << (f & 31));
    }
    __syncthreads();
    int nc = cnt[t]; if (nc > 128) nc = 128;
    double lnt = (double)ln[t];
    for (int c = wave; c < nc; c += 8) {
        int f = (int)cand[(size_t)t * CAP + c];
        const float* wr = Wed + (size_t)f * DIM;
        double p = 0.0;
#pragma unroll
        for (int i = 0; i < 12; ++i) {
            int d = lane + 64 * i;
            p += (double)xrow[d] * (double)wr[d];
        }
        const u16* crow = cclean + (size_t)f * CC;
        int e0 = (int)crow[lane], e1 = (int)crow[lane + 64];
        bool h0 = (e0 != 0xFFFF) && ((bm[e0 >> 5] >> (e0 & 31)) & 1u);
        bool h1 = (e1 != 0xFFFF) && ((bm[e1 >> 5] >> (e1 & 31)) & 1u);
        unsigned long long m0 = __ballot(h0), m1 = __ballot(h1);
        while (m0 | m1) {
            int fu;
            if (m0) {
                int b = __ffsll((long long)m0) - 1; m0 &= m0 - 1;
                fu = __shfl(e0, b);
            } else {
                int b = __ffsll((long long)m1) - 1; m1 &= m1 - 1;
                fu = __shfl(e1, b);
            }
            unsigned long long zm = __ballot(fl[lane] == fu);
            float z = zl[__ffsll((long long)zm) - 1];
            const float* du = WduT + (size_t)fu * DIM;
            double vp = 0.0;
#pragma unroll
            for (int i = 0; i < 12; ++i) {
                int d = lane + 64 * i;
                vp += (double)wr[d] * (double)du[d];
            }
            p += (double)z * vp;
        }
#pragma unroll
        for (int off = 32; off; off >>= 1) p += __shfl_xor(p, off);
        if (lane == 0) {
            double v = (p + tu64[f]) / lnt + (double)bed[f] - td64[f];
            sv[c] = v; si[c] = f;
        }
    }
    __syncthreads();
    bitonic128(sv, si, tid);
    if (tid < KK) {
        vals[(size_t)t * KK + tid] = (float)sv[tid];
        idxs[(size_t)t * KK + tid] = si[tid];
    }
}

// ---------------- conn dedupe + inverse-index build -----------------------------
__global__ __launch_bounds__(128) void dedup_deg_kernel(const int* __restrict__ conn,
                                                        u32* __restrict__ deg) {
    __shared__ int row[CC];
    int fd = blockIdx.x, c = threadIdx.x;
    int v = conn[(size_t)fd * CC + c];
    row[c] = v;
    __syncthreads();
    bool dup = false;
    for (int j = 0; j < c; ++j) dup |= (row[j] == v);
    if (!dup) atomicAdd(&deg[v], 1u);
}

__global__ __launch_bounds__(256) void scan_kernel(const u32* __restrict__ deg,
                                                   u32* __restrict__ offs) {
    __shared__ u32 sdeg[FF];
    __shared__ u32 part[256];
    int tid = threadIdx.x;
    for (int i = tid; i < FF; i += 256) sdeg[i] = deg[i];
    __syncthreads();
    u32 s = 0;
    for (int j = 0; j < 32; ++j) s += sdeg[tid * 32 + j];
    part[tid] = s;
    __syncthreads();
    if (tid == 0) {
        u32 run = 0;
        for (int i = 0; i < 256; ++i) { u32 v = part[i]; part[i] = run; run += v; }
        offs[FF] = run;
    }
    __syncthreads();
    u32 run = part[tid];
    for (int j = 0; j < 32; ++j) { offs[tid * 32 + j] = run; run += sdeg[tid * 32 + j]; }
}

__global__ __launch_bounds__(128) void fill_kernel(const int* __restrict__ conn,
                                                   const u32* __restrict__ offs,
                                                   u32* __restrict__ cursor,
                                                   u16* __restrict__ inv_fd,
                                                   u16* __restrict__ cclean) {
    __shared__ int row[CC];
    int fd = blockIdx.x, c = threadIdx.x;
    int v = conn[(size_t)fd * CC + c];
    row[c] = v;
    __syncthreads();
    bool dup = false;
    for (int j = 0; j < c; ++j) dup |= (row[j] == v);
    cclean[(size_t)fd * CC + c] = dup ? (u16)0xFFFF : (u16)v;
    if (!dup) {
        u32 slot = atomicAdd(&cursor[v], 1u);
        inv_fd[offs[v] + slot] = (u16)fd;
    }
}

// ---------------- vconn chunk -> packed pe[p] = (fd<<16)|bf16(partial) ----------
__global__ __launch_bounds__(256) void vconn_chunk(const u16* __restrict__ Wed16,
                                                   const float* __restrict__ WduT,
                                                   const u32* __restrict__ offs,
                                                   const u16* __restrict__ inv_fd,
                                                   u32* __restrict__ pe,
                                                   int chunk, int first) {
    __shared__ float row[192];
    int fu = blockIdx.x, tid = threadIdx.x;
    if (tid < 192) row[tid] = WduT[(size_t)fu * DIM + chunk * 192 + tid];
    __syncthreads();
    u32 s = offs[fu], e = offs[fu + 1];
    int wave = tid >> 6, lane = tid & 63;
    int sub = lane >> 4, sl = lane & 15;
    for (u32 p0 = s + (u32)wave * 4; p0 < e; p0 += 16) {
        u32 p = p0 + (u32)sub;
        bool valid = p < e;
        float a = 0.f;
        int fd = 0;
        u32 old = 0;
        if (valid) {
            if (first) fd = (int)inv_fd[p];
            else { old = pe[p]; fd = (int)(old >> 16); }
            const u16* wr = Wed16 + (size_t)fd * DIM + chunk * 192;
#pragma unroll
            for (int i = 0; i < 12; ++i)
                a = fmaf(bf2f(wr[sl + 16 * i]), row[sl + 16 * i], a);
        }
        a += __shfl_xor(a, 1);
        a += __shfl_xor(a, 2);
        a += __shfl_xor(a, 4);
        a += __shfl_xor(a, 8);
        if (valid && sl == 0) {
            float v = first ? a : (bf2f((u16)(old & 0xffffu)) + a);
            pe[p] = ((u32)fd << 16) | (u32)f2bf(v);
        }
    }
}

// ---------------- phase2 + select_dn fused: pipelined scatter + u16 radix -------
__global__ __launch_bounds__(256) void phase2sel(const u16* __restrict__ X16,
                                                 const float* __restrict__ vals_up,
                                                 const int* __restrict__ idx_up,
                                                 const u32* __restrict__ offs,
                                                 const u32* __restrict__ pe,
                                                 const float* __restrict__ tuF,
                                                 const float* __restrict__ c2F,
                                                 const float* __restrict__ ln,
                                                 u16* __restrict__ cand,
                                                 int* __restrict__ cnt) {
    __shared__ float acc[FF];          // 32 KB
    __shared__ u16 keys[FF];           // 16 KB
    __shared__ float zl[KK];
    __shared__ u32 offs_s[KK];
    __shared__ u32 cum[KK + 1];
    __shared__ u32 hist[256];
    __shared__ int eqidx[256];
    __shared__ u32 shG, shE;
    __shared__ int shB, shK;
    int t = blockIdx.x, tid = threadIdx.x;
    for (int i = tid; i < FF; i += 256) acc[i] = 0.f;
    if (tid < KK) {
        int f = idx_up[(size_t)t * KK + tid];
        zl[tid] = vals_up[(size_t)t * KK + tid];
        offs_s[tid] = offs[f];
        cum[tid] = offs[f + 1] - offs[f];   // deg, prefixed below
    }
    __syncthreads();
    if (tid == 0) {
        u32 run = 0;
        for (int j = 0; j < KK; ++j) { u32 d = cum[j]; cum[j] = run; run += d; }
        cum[KK] = run;
    }
    __syncthreads();
    u32 E = cum[KK];
    // scatter: flattened entry range, 4-deep load pipeline
    for (u32 q0 = tid; q0 < E; q0 += 1024) {
        u32 vv[4]; float zz[4];
        int nv = 0;
        u32 qq = q0;
#pragma unroll
        for (int u = 0; u < 4; ++u) {
            if (qq < E) {
                int j = 0;
#pragma unroll
                for (int b = 32; b; b >>= 1)
                    if (j + b < KK && cum[j + b] <= qq) j += b;
                u32 p = offs_s[j] + (qq - cum[j]);
                vv[nv] = pe[p];
                zz[nv] = zl[j];
                ++nv;
            }
            qq += 256;
        }
        for (int u = 0; u < nv; ++u)
            atomicAdd(&acc[vv[u] >> 16], zz[u] * bf2f((u16)(vv[u] & 0xffffu)));
    }
    __syncthreads();
    // epilogue -> bf16 ordering keys
    float lnv = ln[t];
    const ushort4* xs = (const ushort4*)(X16 + (size_t)t * FF);
    for (int i = tid; i < FF / 4; i += 256) {
        ushort4 u = xs[i];
        float4 tu = ((const float4*)tuF)[i];
        float4 c2 = ((const float4*)c2F)[i];
        int i4 = i * 4;
        float v0 = (bf2f(u.x) + acc[i4]     + tu.x) / lnv + c2.x;
        float v1 = (bf2f(u.y) + acc[i4 + 1] + tu.y) / lnv + c2.y;
        float v2 = (bf2f(u.z) + acc[i4 + 2] + tu.z) / lnv + c2.z;
        float v3 = (bf2f(u.w) + acc[i4 + 3] + tu.w) / lnv + c2.w;
        keys[i4]     = bfkey(f2bf(v0));
        keys[i4 + 1] = bfkey(f2bf(v1));
        keys[i4 + 2] = bfkey(f2bf(v2));
        keys[i4 + 3] = bfkey(f2bf(v3));
    }
    __syncthreads();
    radix_collect_u16(keys, hist, eqidx, KSEL_DN, cand + (size_t)t * CAP, cnt, t,
                      &shG, &shE, &shB, &shK);
}

// ---------------- both sparse decodes in one launch -----------------------------
__global__ __launch_bounds__(256) void decode_both(const float* __restrict__ vals_up,
                                                   const int* __restrict__ idx_up,
                                                   const float* __restrict__ vals_dn,
                                                   const int* __restrict__ idx_dn,
                                                   const float* __restrict__ WduT,
                                                   const float* __restrict__ WddT,
                                                   const float* __restrict__ bdu,
                                                   const float* __restrict__ bdd,
                                                   float* __restrict__ outp) {
    __shared__ float z[KK];
    __shared__ int fidx[KK];
    int b = blockIdx.x, tid = threadIdx.x;
    int which = b >> 10, t = b & 1023;
    const float* vals = which ? vals_dn : vals_up;
    const int* idxs = which ? idx_dn : idx_up;
    const float* WdT = which ? WddT : WduT;
    const float* bd = which ? bdd : bdu;
    float* o = outp + (size_t)which * NTOK * DIM + (size_t)t * DIM;
    if (tid < KK) { z[tid] = vals[(size_t)t * KK + tid]; fidx[tid] = idxs[(size_t)t * KK + tid]; }
    __syncthreads();
    float a0 = 0.f, a1 = 0.f, a2 = 0.f;
    for (int j = 0; j < KK; ++j) {
        const float* wr = WdT + (size_t)fidx[j] * DIM;
        float zj = z[j];
        a0 = fmaf(zj, wr[tid], a0);
        a1 = fmaf(zj, wr[tid + 256], a1);
        a2 = fmaf(zj, wr[tid + 512], a2);
    }
    o[tid]       = a0 + bd[tid];
    o[tid + 256] = a1 + bd[tid + 256];
    o[tid + 512] = a2 + bd[tid + 512];
}

extern "C" void kernel_launch(void* const* d_in, const int* in_sizes, int n_in,
                              void* d_out, int out_size, void* d_ws, size_t ws_size,
                              hipStream_t stream) {
    const float* x0  = (const float*)d_in[0];
    const float* xu  = (const float*)d_in[1];
    const float* ln  = (const float*)d_in[2];
    const float* Weu = (const float*)d_in[3];
    const float* beu = (const float*)d_in[4];
    const float* Wdu = (const float*)d_in[5];
    const float* bdu = (const float*)d_in[6];
    const float* Wed = (const float*)d_in[7];
    const float* bed = (const float*)d_in[8];
    const float* Wdd = (const float*)d_in[9];
    const float* bdd = (const float*)d_in[10];
    const int* conn = (const int*)d_in[11];
    float* out = (float*)d_out;

    // workspace carve-up (~62.7 MiB)
    char* w = (char*)d_ws;
    size_t off = 0;
    auto take = [&](size_t bytes) { char* p = w + off; off = (off + bytes + 255) & ~(size_t)255; return p; };
    u16*   X16     = (u16*)take((size_t)NTOK * FF * 2);        // 16 MiB
    u16*   B16     = (u16*)take((size_t)FF * DIM * 2);         // 12 MiB (Weu16 then Wed16)
    float* WddT    = (float*)X16;                              // 24 MiB alias over X16+B16
    float* WduT    = (float*)take((size_t)FF * DIM * 4);       // 24 MiB
    u16*   A16     = (u16*)take((size_t)NTOK * DIM * 2);       // 1.5 MiB (shared up/down)
    u16*   inv_fd  = (u16*)take((size_t)FF * CC * 2);          // 2 MiB
    u16*   cclean  = (u16*)take((size_t)FF * CC * 2);          // 2 MiB
    u32*   pe      = (u32*)take((size_t)FF * CC * 4);          // 4 MiB packed entries
    u16*   cand_u  = (u16*)take((size_t)NTOK * CAP * 2);
    u16*   cand_d  = (u16*)take((size_t)NTOK * CAP * 2);
    int*   cnt_u   = (int*)take(NTOK * 4);
    int*   cnt_d   = (int*)take(NTOK * 4);
    float* vals_up = (float*)take((size_t)NTOK * KK * 4);
    int*   idx_up  = (int*)take((size_t)NTOK * KK * 4);
    float* vals_dn = (float*)take((size_t)NTOK * KK * 4);
    int*   idx_dn  = (int*)take((size_t)NTOK * KK * 4);
    float* sF      = (float*)take(FF * 4);
    float* tuF     = (float*)take(FF * 4);
    float* c2F     = (float*)take(FF * 4);
    double* s64    = (double*)take(FF * 8);
    double* tu64   = (double*)take(FF * 8);
    double* td64   = (double*)take(FF * 8);
    u32*   deg     = (u32*)take(FF * 4);
    u32*   cursor  = (u32*)take(FF * 4);
    u32*   offs    = (u32*)take((FF + 8) * 4);

    dim3 tgrid(FF / 32, DIM / 32), tblk(32, 8);
    dim3 ggrid(FF / 128, NTOK / 128);
    int nA4 = NTOK * DIM / 4, nB4 = FF * DIM / 4;

    // prep
    transpose_kernel<<<tgrid, tblk, 0, stream>>>(Wdu, WduT);
    bias_kernel<<<FF, 64, 0, stream>>>(Weu, Wed, bdu, bdd, bed, sF, tuF, c2F,
                                       s64, tu64, td64);
    hipMemsetAsync(deg, 0, 2 * FF * sizeof(u32), stream);  // deg + cursor (adjacent)
    dedup_deg_kernel<<<FF, CC, 0, stream>>>(conn, deg);
    scan_kernel<<<1, 256, 0, stream>>>(deg, offs);
    fill_kernel<<<FF, CC, 0, stream>>>(conn, offs, cursor, inv_fd, cclean);

    // upstream
    convert_kernel<<<(nA4 + 255) / 256, 256, 0, stream>>>(xu, A16, nA4);
    convert_kernel<<<(nB4 + 255) / 256, 256, 0, stream>>>(Weu, B16, nB4);
    gemm_mfma<0><<<ggrid, 256, 0, stream>>>(A16, B16, X16, sF, beu);
    select_up_kernel<<<NTOK, 256, 0, stream>>>(X16, cand_u, cnt_u);
    fixup_up<<<NTOK, 512, 0, stream>>>(xu, Weu, s64, beu, cand_u, cnt_u, vals_up, idx_up);

    // downstream
    convert_kernel<<<(nA4 + 255) / 256, 256, 0, stream>>>(x0, A16, nA4);
    convert_kernel<<<(nB4 + 255) / 256, 256, 0, stream>>>(Wed, B16, nB4);
    gemm_mfma<1><<<ggrid, 256, 0, stream>>>(A16, B16, X16, sF, beu);
    vconn_chunk<<<FF, 256, 0, stream>>>(B16, WduT, offs, inv_fd, pe, 0, 1);
    vconn_chunk<<<FF, 256, 0, stream>>>(B16, WduT, offs, inv_fd, pe, 1, 0);
    vconn_chunk<<<FF, 256, 0, stream>>>(B16, WduT, offs, inv_fd, pe, 2, 0);
    vconn_chunk<<<FF, 256, 0, stream>>>(B16, WduT, offs, inv_fd, pe, 3, 0);
    phase2sel<<<NTOK, 256, 0, stream>>>(X16, vals_up, idx_up, offs, pe,
                                        tuF, c2F, ln, cand_d, cnt_d);
    fixup_dn<<<NTOK, 512, 0, stream>>>(x0, Wed, WduT, tu64, td64, bed, ln, cclean,
                                       vals_up, idx_up, cand_d, cnt_d, vals_dn, idx_dn);

    // WddT transpose (clobbers X16|B16, both dead now) + both decodes
    transpose_kernel<<<tgrid, tblk, 0, stream>>>(Wdd, WddT);
    decode_both<<<2 * NTOK, 256, 0, stream>>>(vals_up, idx_up, vals_dn, idx_dn,
                                              WduT, WddT, bdu, bdd, out);
}

// Round 8
// 781.412 us; speedup vs baseline: 1.1270x; 1.1270x over previous
//
#include <hip/hip_runtime.h>

// SCAESuite R8: low-LDS fused phase2sel (in-place keys, wave-per-segment scatter),
// parallel suffix-sum radix thresholds, bf16 decode weights.
// n=1024 tokens, D=768, F=8192, K=64, C=128. Inputs f32, output f32.
//  - gemm_mfma: bf16 16x16x32 MFMA, 128x128 tile -> X bf16 (selection only)
//  - vconn: 4 D-chunk launches (3MB gather set, L2-resident), packed pe entries
//  - phase2sel: ~35KB LDS (4 blocks/CU), keys written in place over acc
//  - radix: 2-pass u16, threshold via parallel suffix scan (no serial tid0 loop)
//  - fixup_*: 512 threads, exact f64 rescore (R4-proven values), bitonic top-64
//  - decode_both: bf16 weight rows (halved gather traffic)
//  - ws ~62.7 MiB; WduT16 aliases B16, WddT16 aliases X16

#define NTOK 1024
#define DIM  768
#define FF   8192
#define KK   64
#define CC   128
#define KSEL_UP 80
#define KSEL_DN 96
#define CAP  128

typedef unsigned short u16;
typedef unsigned int   u32;
typedef __attribute__((ext_vector_type(8))) short short8;
typedef __attribute__((ext_vector_type(4))) float floatx4;

__device__ __forceinline__ float bits2f(u32 v) {
    float f; __builtin_memcpy(&f, &v, 4); return f;
}
__device__ __forceinline__ float bf2f(u16 u) { return bits2f(((u32)u) << 16); }
__device__ __forceinline__ u16 f2bf(float f) {
    u32 u; __builtin_memcpy(&u, &f, 4);
    u32 lsb = (u >> 16) & 1u;
    u += 0x7fffu + lsb;
    return (u16)(u >> 16);
}
// monotone bf16-bits -> u16 ordering key
__device__ __forceinline__ u16 bfkey(u16 b) {
    return (b & 0x8000u) ? (u16)~b : (u16)(b | 0x8000u);
}

// ---------------- f32 -> bf16 bulk convert --------------------------------------
__global__ __launch_bounds__(256) void convert_kernel(const float* __restrict__ src,
                                                      u16* __restrict__ dst, int n4) {
    int i = blockIdx.x * 256 + threadIdx.x;
    if (i < n4) {
        float4 v = ((const float4*)src)[i];
        ushort4 o;
        o.x = f2bf(v.x); o.y = f2bf(v.y); o.z = f2bf(v.z); o.w = f2bf(v.w);
        ((ushort4*)dst)[i] = o;
    }
}

// ---------------- transpose: f32 [DIM][FF] -> f32 [FF][DIM] ---------------------
__global__ __launch_bounds__(256) void transpose_kernel(const float* __restrict__ in,
                                                        float* __restrict__ out) {
    __shared__ float tile[32][33];
    int f0 = blockIdx.x * 32, d0 = blockIdx.y * 32;
    int tx = threadIdx.x, ty = threadIdx.y;
#pragma unroll
    for (int i = 0; i < 4; ++i)
        tile[ty + 8 * i][tx] = in[(size_t)(d0 + ty + 8 * i) * FF + f0 + tx];
    __syncthreads();
#pragma unroll
    for (int i = 0; i < 4; ++i)
        out[(size_t)(f0 + ty + 8 * i) * DIM + d0 + tx] = tile[tx][ty + 8 * i];
}

// ---------------- transpose: f32 [DIM][FF] -> bf16 [FF][DIM] --------------------
__global__ __launch_bounds__(256) void transpose16_kernel(const float* __restrict__ in,
                                                          u16* __restrict__ out) {
    __shared__ float tile[32][33];
    int f0 = blockIdx.x * 32, d0 = blockIdx.y * 32;
    int tx = threadIdx.x, ty = threadIdx.y;
#pragma unroll
    for (int i = 0; i < 4; ++i)
        tile[ty + 8 * i][tx] = in[(size_t)(d0 + ty + 8 * i) * FF + f0 + tx];
    __syncthreads();
#pragma unroll
    for (int i = 0; i < 4; ++i)
        out[(size_t)(f0 + ty + 8 * i) * DIM + d0 + tx] = f2bf(tile[tx][ty + 8 * i]);
}

// ---------------- bias dots (f32 + f64 copies + c2 = bed - t_dn) ----------------
__global__ __launch_bounds__(64) void bias_kernel(const float* __restrict__ Weu,
                                                  const float* __restrict__ Wed,
                                                  const float* __restrict__ bdu,
                                                  const float* __restrict__ bdd,
                                                  const float* __restrict__ bed,
                                                  float* __restrict__ sF,
                                                  float* __restrict__ tuF,
                                                  float* __restrict__ c2F,
                                                  double* __restrict__ s64,
                                                  double* __restrict__ tu64,
                                                  double* __restrict__ td64) {
    int f = blockIdx.x, lane = threadIdx.x;
    double su = 0.0, tu = 0.0, td = 0.0;
    for (int i = lane; i < DIM; i += 64) {
        double bu = (double)bdu[i], bd = (double)bdd[i];
        su += (double)Weu[(size_t)f * DIM + i] * bu;
        double w = (double)Wed[(size_t)f * DIM + i];
        tu += w * bu;
        td += w * bd;
    }
#pragma unroll
    for (int off = 32; off; off >>= 1) {
        su += __shfl_xor(su, off);
        tu += __shfl_xor(tu, off);
        td += __shfl_xor(td, off);
    }
    if (lane == 0) {
        sF[f] = (float)su; tuF[f] = (float)tu;
        c2F[f] = (float)((double)bed[f] - td);
        s64[f] = su; tu64[f] = tu; td64[f] = td;
    }
}

// ---------------- bf16 MFMA GEMM: X[t,f] = sum_d A[t,d]*B[f,d] ------------------
template <int MODE>
__global__ __launch_bounds__(256) void gemm_mfma(const u16* __restrict__ A16,
                                                 const u16* __restrict__ B16,
                                                 u16* __restrict__ Xout,
                                                 const float* __restrict__ sF,
                                                 const float* __restrict__ b_enc) {
    __shared__ __align__(16) u16 As[128 * 40];
    __shared__ __align__(16) u16 Bs[128 * 40];
    int tid = threadIdx.x;
    int wave = tid >> 6, lane = tid & 63;
    int lm = lane & 15, quad = lane >> 4;
    int m0 = blockIdx.y * 128, n0 = blockIdx.x * 128;
    int wm = (wave >> 1) * 64, wn = (wave & 1) * 64;
    floatx4 acc[4][4];
#pragma unroll
    for (int i = 0; i < 4; ++i)
#pragma unroll
        for (int j = 0; j < 4; ++j)
            acc[i][j] = (floatx4){0.f, 0.f, 0.f, 0.f};
    int r = tid >> 2;
    int s = (tid & 3) * 8;
    const u16* gA = A16 + (size_t)(m0 + r) * DIM + s;
    const u16* gB = B16 + (size_t)(n0 + r) * DIM + s;
    for (int k0 = 0; k0 < DIM; k0 += 32) {
        __syncthreads();
        *(int4*)&As[r * 40 + s]          = *(const int4*)(gA + k0);
        *(int4*)&As[(r + 64) * 40 + s]   = *(const int4*)(gA + (size_t)64 * DIM + k0);
        *(int4*)&Bs[r * 40 + s]          = *(const int4*)(gB + k0);
        *(int4*)&Bs[(r + 64) * 40 + s]   = *(const int4*)(gB + (size_t)64 * DIM + k0);
        __syncthreads();
        short8 af[4], bfr[4];
#pragma unroll
        for (int mi = 0; mi < 4; ++mi)
            af[mi] = *(const short8*)&As[(wm + mi * 16 + lm) * 40 + quad * 8];
#pragma unroll
        for (int ni = 0; ni < 4; ++ni)
            bfr[ni] = *(const short8*)&Bs[(wn + ni * 16 + lm) * 40 + quad * 8];
#pragma unroll
        for (int mi = 0; mi < 4; ++mi)
#pragma unroll
            for (int ni = 0; ni < 4; ++ni)
                acc[mi][ni] = __builtin_amdgcn_mfma_f32_16x16x32_bf16(
                    af[mi], bfr[ni], acc[mi][ni], 0, 0, 0);
    }
#pragma unroll
    for (int ni = 0; ni < 4; ++ni) {
        int col = n0 + wn + ni * 16 + lm;
        float sub = 0.f, bb = 0.f;
        if (MODE == 0) { sub = sF[col]; bb = b_enc[col]; }
#pragma unroll
        for (int mi = 0; mi < 4; ++mi) {
#pragma unroll
            for (int reg = 0; reg < 4; ++reg) {
                int row = m0 + wm + mi * 16 + quad * 4 + reg;
                float v = acc[mi][ni][reg];
                if (MODE == 0) { v = v - sub + bb; v = v > 0.f ? v : 0.f; }
                Xout[(size_t)row * FF + col] = f2bf(v);
            }
        }
    }
}

// ---------------- parallel threshold find: suffix scan over hist[256] -----------
// After: sc[0] = threshold bin, sc[1] = remaining count within bin. Destroys hist.
__device__ void find_threshold(u32* hist, int k, u32* sc) {
    int tid = threadIdx.x;
    for (int st = 1; st < 256; st <<= 1) {
        u32 v = 0;
        if (tid < 256) {
            v = hist[tid];
            if (tid + st < 256) v += hist[tid + st];
        }
        __syncthreads();
        if (tid < 256) hist[tid] = v;
        __syncthreads();
    }
    if (tid < 256) {
        u32 ge = hist[tid];
        u32 gn = (tid < 255) ? hist[tid + 1] : 0u;
        if ((int)ge >= k && (int)gn < k) { sc[0] = (u32)tid; sc[1] = (u32)(k - (int)gn); }
    }
    __syncthreads();
}

// ---------------- 2-pass u16 radix collect (keys: low 16 bits of keys[i]) -------
template <typename KT>
__device__ void radix_collect(const KT* __restrict__ keys, u32* hist, int* eqidx,
                              u32* sc, int ksel, u16* cr, int* cnt_out, int row) {
    int tid = threadIdx.x;
    if (tid < 256) hist[tid] = 0;
    __syncthreads();
    for (int i = tid; i < FF; i += 256) atomicAdd(&hist[((u32)keys[i] & 0xffffu) >> 8], 1u);
    __syncthreads();
    find_threshold(hist, ksel, sc);
    int hb = (int)sc[0], k1 = (int)sc[1];
    if (tid < 256) hist[tid] = 0;
    __syncthreads();
    for (int i = tid; i < FF; i += 256) {
        u32 k = (u32)keys[i] & 0xffffu;
        if ((int)(k >> 8) == hb) atomicAdd(&hist[k & 255u], 1u);
    }
    __syncthreads();
    find_threshold(hist, k1, sc);
    u32 T = ((u32)hb << 8) | sc[0];
    if (tid == 0) { sc[2] = 0; sc[3] = 0; }
    __syncthreads();
    for (int i = tid; i < FF; i += 256) {
        u32 k = (u32)keys[i] & 0xffffu;
        if (k > T) {
            u32 p = atomicAdd(&sc[2], 1u);
            if (p < CAP) cr[p] = (u16)i;
        } else if (k == T) {
            u32 p = atomicAdd(&sc[3], 1u);
            if (p < 256) eqidx[p] = i;
        }
    }
    __syncthreads();
    if (tid == 0) {
        int G = (int)sc[2]; if (G > CAP) G = CAP;
        int ne = (int)sc[3]; if (ne > 256) ne = 256;
        int total = G;
        for (int q = 0; q < ne && total < CAP; ++q) cr[total++] = (u16)eqidx[q];
        cnt_out[row] = total;
    }
}

// ---------------- select_up: u16 keys in LDS + parallel 2-pass radix ------------
__global__ __launch_bounds__(256) void select_up_kernel(const u16* __restrict__ X16,
                                                        u16* __restrict__ cand,
                                                        int* __restrict__ cnt) {
    __shared__ u16 keys[FF];
    __shared__ u32 hist[256];
    __shared__ int eqidx[256];
    __shared__ u32 sc[4];
    const int row = blockIdx.x, tid = threadIdx.x;
    const ushort4* src = (const ushort4*)(X16 + (size_t)row * FF);
    for (int i = tid; i < FF / 4; i += 256) {
        ushort4 u = src[i];
        keys[i * 4]     = bfkey(u.x);
        keys[i * 4 + 1] = bfkey(u.y);
        keys[i * 4 + 2] = bfkey(u.z);
        keys[i * 4 + 3] = bfkey(u.w);
    }
    __syncthreads();
    radix_collect<u16>(keys, hist, eqidx, sc, KSEL_UP, cand + (size_t)row * CAP, cnt, row);
}

// ---------------- bitonic sort of 128 (desc by val, asc idx) --------------------
__device__ __forceinline__ bool sort_before(double av, int ai, double bv, int bi) {
    return (av > bv) || (av == bv && ai < bi);
}
__device__ void bitonic128(double* sv, int* si, int tid) {
    for (int k = 2; k <= 128; k <<= 1) {
        for (int j = k >> 1; j > 0; j >>= 1) {
            __syncthreads();
            if (tid < 64) {
                int i = ((tid & ~(j - 1)) << 1) | (tid & (j - 1));
                int l = i, rr = i + j;
                bool bfirst = sort_before(sv[rr], si[rr], sv[l], si[l]);
                bool doswap = ((i & k) == 0) ? bfirst : !bfirst;
                if (doswap) {
                    double tv = sv[l]; sv[l] = sv[rr]; sv[rr] = tv;
                    int ti = si[l]; si[l] = si[rr]; si[rr] = ti;
                }
            }
        }
    }
    __syncthreads();
}

// ---------------- exact rescore (up), 512 threads -------------------------------
__global__ __launch_bounds__(512) void fixup_up(const float* __restrict__ xu,
                                                const float* __restrict__ Weu,
                                                const double* __restrict__ s64,
                                                const float* __restrict__ beu,
                                                const u16* __restrict__ cand,
                                                const int* __restrict__ cnt,
                                                float* __restrict__ vals,
                                                int* __restrict__ idxs) {
    __shared__ float xrow[DIM];
    __shared__ double sv[128];
    __shared__ int si[128];
    int t = blockIdx.x, tid = threadIdx.x, wave = tid >> 6, lane = tid & 63;
    for (int i = tid; i < DIM; i += 512) xrow[i] = xu[(size_t)t * DIM + i];
    for (int c = tid; c < 128; c += 512) { sv[c] = -1.0e300; si[c] = 0x7fffffff; }
    __syncthreads();
    int nc = cnt[t]; if (nc > 128) nc = 128;
    for (int c = wave; c < nc; c += 8) {
        int f = (int)cand[(size_t)t * CAP + c];
        const float* wr = Weu + (size_t)f * DIM;
        double p = 0.0;
#pragma unroll
        for (int i = 0; i < 12; ++i) {
            int d = lane + 64 * i;
            p += (double)xrow[d] * (double)wr[d];
        }
#pragma unroll
        for (int off = 32; off; off >>= 1) p += __shfl_xor(p, off);
        if (lane == 0) {
            double v = p - s64[f] + (double)beu[f];
            v = v > 0.0 ? v : 0.0;
            sv[c] = v; si[c] = f;
        }
    }
    __syncthreads();
    bitonic128(sv, si, tid);
    if (tid < KK) {
        vals[(size_t)t * KK + tid] = (float)sv[tid];
        idxs[(size_t)t * KK + tid] = si[tid];
    }
}

// ---------------- exact rescore (down), 512 threads -----------------------------
__global__ __launch_bounds__(512) void fixup_dn(const float* __restrict__ x0,
                                                const float* __restrict__ Wed,
                                                const float* __restrict__ WduT,
                                                const double* __restrict__ tu64,
                                                const double* __restrict__ td64,
                                                const float* __restrict__ bed,
                                                const float* __restrict__ ln,
                                                const u16* __restrict__ cclean,
                                                const float* __restrict__ vals_up,
                                                const int* __restrict__ idx_up,
                                                const u16* __restrict__ cand,
                                                const int* __restrict__ cnt,
                                                float* __restrict__ vals,
                                                int* __restrict__ idxs) {
    __shared__ float xrow[DIM];
    __shared__ u32 bm[256];
    __shared__ int fl[KK];
    __shared__ float zl[KK];
    __shared__ double sv[128];
    __shared__ int si[128];
    int t = blockIdx.x, tid = threadIdx.x, wave = tid >> 6, lane = tid & 63;
    for (int i = tid; i < DIM; i += 512) xrow[i] = x0[(size_t)t * DIM + i];
    if (tid < 256) bm[tid] = 0;
    for (int c = tid; c < 128; c += 512) { sv[c] = -1.0e300; si[c] = 0x7fffffff; }
    __syncthreads();
    if (tid < KK) {
        int f = idx_up[(size_t)t * KK + tid];
        fl[tid] = f; zl[tid] = vals_up[(size_t)t * KK + tid];
        atomicOr(&bm[f >> 5], 1u << (f & 31));
    }
    __syncthreads();
    int nc = cnt[t]; if (nc > 128) nc = 128;
    double lnt = (double)ln[t];
    for (int c = wave; c < nc; c += 8) {
        int f = (int)cand[(size_t)t * CAP + c];
        const float* wr = Wed + (size_t)f * DIM;
        double p = 0.0;
#pragma unroll
        for (int i = 0; i < 12; ++i) {
            int d = lane + 64 * i;
            p += (double)xrow[d] * (double)wr[d];
        }
        const u16* crow = cclean + (size_t)f * CC;
        int e0 = (int)crow[lane], e1 = (int)crow[lane + 64];
        bool h0 = (e0 != 0xFFFF) && ((bm[e0 >> 5] >> (e0 & 31)) & 1u);
        bool h1 = (e1 != 0xFFFF) && ((bm[e1 >> 5] >> (e1 & 31)) & 1u);
        unsigned long long m0 = __ballot(h0), m1 = __ballot(h1);
        while (m0 | m1) {
            int fu;
            if (m0) {
                int b = __ffsll((long long)m0) - 1; m0 &= m0 - 1;
                fu = __shfl(e0, b);
            } else {
                int b = __ffsll((long long)m1) - 1; m1 &= m1 - 1;
                fu = __shfl(e1, b);
            }
            unsigned long long zm = __ballot(fl[lane] == fu);
            float z = zl[__ffsll((long long)zm) - 1];
            const float* du = WduT + (size_t)fu * DIM;
            double vp = 0.0;
#pragma unroll
            for (int i = 0; i < 12; ++i) {
                int d = lane + 64 * i;
                vp += (double)wr[d] * (double)du[d];
            }
            p += (double)z * vp;
        }
#pragma unroll
        for (int off = 32; off; off >>= 1) p += __shfl_xor(p, off);
        if (lane == 0) {
            double v = (p + tu64[f]) / lnt + (double)bed[f] - td64[f];
            sv[c] = v; si[c] = f;
        }
    }
    __syncthreads();
    bitonic128(sv, si, tid);
    if (tid < KK) {
        vals[(size_t)t * KK + tid] = (float)sv[tid];
        idxs[(size_t)t * KK + tid] = si[tid];
    }
}

// ---------------- conn dedupe + inverse-index build -----------------------------
__global__ __launch_bounds__(128) void dedup_deg_kernel(const int* __restrict__ conn,
                                                        u32* __restrict__ deg) {
    __shared__ int row[CC];
    int fd = blockIdx.x, c = threadIdx.x;
    int v = conn[(size_t)fd * CC + c];
    row[c] = v;
    __syncthreads();
    bool dup = false;
    for (int j = 0; j < c; ++j) dup |= (row[j] == v);
    if (!dup) atomicAdd(&deg[v], 1u);
}

__global__ __launch_bounds__(256) void scan_kernel(const u32* __restrict__ deg,
                                                   u32* __restrict__ offs) {
    __shared__ u32 sdeg[FF];
    __shared__ u32 part[256];
    int tid = threadIdx.x;
    for (int i = tid; i < FF; i += 256) sdeg[i] = deg[i];
    __syncthreads();
    u32 s = 0;
    for (int j = 0; j < 32; ++j) s += sdeg[tid * 32 + j];
    part[tid] = s;
    __syncthreads();
    if (tid == 0) {
        u32 run = 0;
        for (int i = 0; i < 256; ++i) { u32 v = part[i]; part[i] = run; run += v; }
        offs[FF] = run;
    }
    __syncthreads();
    u32 run = part[tid];
    for (int j = 0; j < 32; ++j) { offs[tid * 32 + j] = run; run += sdeg[tid * 32 + j]; }
}

__global__ __launch_bounds__(128) void fill_kernel(const int* __restrict__ conn,
                                                   const u32* __restrict__ offs,
                                                   u32* __restrict__ cursor,
                                                   u16* __restrict__ inv_fd,
                                                   u16* __restrict__ cclean) {
    __shared__ int row[CC];
    int fd = blockIdx.x, c = threadIdx.x;
    int v = conn[(size_t)fd * CC + c];
    row[c] = v;
    __syncthreads();
    bool dup = false;
    for (int j = 0; j < c; ++j) dup |= (row[j] == v);
    cclean[(size_t)fd * CC + c] = dup ? (u16)0xFFFF : (u16)v;
    if (!dup) {
        u32 slot = atomicAdd(&cursor[v], 1u);
        inv_fd[offs[v] + slot] = (u16)fd;
    }
}

// ---------------- vconn chunk -> packed pe[p] = (fd<<16)|bf16(partial) ----------
__global__ __launch_bounds__(256) void vconn_chunk(const u16* __restrict__ Wed16,
                                                   const float* __restrict__ WduT,
                                                   const u32* __restrict__ offs,
                                                   const u16* __restrict__ inv_fd,
                                                   u32* __restrict__ pe,
                                                   int chunk, int first) {
    __shared__ float row[192];
    int fu = blockIdx.x, tid = threadIdx.x;
    if (tid < 192) row[tid] = WduT[(size_t)fu * DIM + chunk * 192 + tid];
    __syncthreads();
    u32 s = offs[fu], e = offs[fu + 1];
    int wave = tid >> 6, lane = tid & 63;
    int sub = lane >> 4, sl = lane & 15;
    for (u32 p0 = s + (u32)wave * 4; p0 < e; p0 += 16) {
        u32 p = p0 + (u32)sub;
        bool valid = p < e;
        float a = 0.f;
        int fd = 0;
        u32 old = 0;
        if (valid) {
            if (first) fd = (int)inv_fd[p];
            else { old = pe[p]; fd = (int)(old >> 16); }
            const u16* wr = Wed16 + (size_t)fd * DIM + chunk * 192;
#pragma unroll
            for (int i = 0; i < 12; ++i)
                a = fmaf(bf2f(wr[sl + 16 * i]), row[sl + 16 * i], a);
        }
        a += __shfl_xor(a, 1);
        a += __shfl_xor(a, 2);
        a += __shfl_xor(a, 4);
        a += __shfl_xor(a, 8);
        if (valid && sl == 0) {
            float v = first ? a : (bf2f((u16)(old & 0xffffu)) + a);
            pe[p] = ((u32)fd << 16) | (u32)f2bf(v);
        }
    }
}

// ---------------- phase2 + select_dn fused: ~35KB LDS, in-place keys ------------
__global__ __launch_bounds__(256) void phase2sel(const u16* __restrict__ X16,
                                                 const float* __restrict__ vals_up,
                                                 const int* __restrict__ idx_up,
                                                 const u32* __restrict__ offs,
                                                 const u32* __restrict__ pe,
                                                 const float* __restrict__ tuF,
                                                 const float* __restrict__ c2F,
                                                 const float* __restrict__ ln,
                                                 u16* __restrict__ cand,
                                                 int* __restrict__ cnt) {
    __shared__ u32 accbits[FF];        // 32 KB: f32 acc, then u16 keys in place
    __shared__ float zl[KK];
    __shared__ u32 offs_s[KK];
    __shared__ u32 ends_s[KK];
    __shared__ u32 hist[256];
    __shared__ int eqidx[256];
    __shared__ u32 sc[4];
    float* facc = (float*)accbits;
    int t = blockIdx.x, tid = threadIdx.x, wave = tid >> 6, lane = tid & 63;
    for (int i = tid; i < FF; i += 256) accbits[i] = 0u;
    if (tid < KK) {
        int f = idx_up[(size_t)t * KK + tid];
        zl[tid] = vals_up[(size_t)t * KK + tid];
        offs_s[tid] = offs[f];
        ends_s[tid] = offs[f + 1];
    }
    __syncthreads();
    // wave-per-segment scatter: 4 segments in flight, 3 loads pre-issued/lane
    for (int j = wave; j < KK; j += 4) {
        u32 s = offs_s[j], e = ends_s[j];
        float zj = zl[j];
        u32 p = s + (u32)lane;
        u32 v0 = 0, v1 = 0, v2 = 0;
        bool h0 = p < e, h1 = p + 64 < e, h2 = p + 128 < e;
        if (h0) v0 = pe[p];
        if (h1) v1 = pe[p + 64];
        if (h2) v2 = pe[p + 128];
        if (h0) atomicAdd(&facc[v0 >> 16], zj * bf2f((u16)(v0 & 0xffffu)));
        if (h1) atomicAdd(&facc[v1 >> 16], zj * bf2f((u16)(v1 & 0xffffu)));
        if (h2) atomicAdd(&facc[v2 >> 16], zj * bf2f((u16)(v2 & 0xffffu)));
        for (u32 q = p + 192; q < e; q += 64) {
            u32 v = pe[q];
            atomicAdd(&facc[v >> 16], zj * bf2f((u16)(v & 0xffffu)));
        }
    }
    __syncthreads();
    // epilogue + in-place key conversion (each index owned by one thread)
    float lnv = ln[t];
    const ushort4* xs = (const ushort4*)(X16 + (size_t)t * FF);
    const float4* tu4 = (const float4*)tuF;
    const float4* c24 = (const float4*)c2F;
    for (int i = tid; i < FF / 4; i += 256) {
        ushort4 u = xs[i];
        float4 tu = tu4[i], c2 = c24[i];
        int i4 = i * 4;
        float a0 = facc[i4], a1 = facc[i4 + 1], a2 = facc[i4 + 2], a3 = facc[i4 + 3];
        accbits[i4]     = (u32)bfkey(f2bf((bf2f(u.x) + a0 + tu.x) / lnv + c2.x));
        accbits[i4 + 1] = (u32)bfkey(f2bf((bf2f(u.y) + a1 + tu.y) / lnv + c2.y));
        accbits[i4 + 2] = (u32)bfkey(f2bf((bf2f(u.z) + a2 + tu.z) / lnv + c2.z));
        accbits[i4 + 3] = (u32)bfkey(f2bf((bf2f(u.w) + a3 + tu.w) / lnv + c2.w));
    }
    __syncthreads();
    radix_collect<u32>(accbits, hist, eqidx, sc, KSEL_DN, cand + (size_t)t * CAP, cnt, t);
}

// ---------------- both sparse decodes, bf16 weight rows -------------------------
__global__ __launch_bounds__(256) void decode_both(const float* __restrict__ vals_up,
                                                   const int* __restrict__ idx_up,
                                                   const float* __restrict__ vals_dn,
                                                   const int* __restrict__ idx_dn,
                                                   const u16* __restrict__ WduT16,
                                                   const u16* __restrict__ WddT16,
                                                   const float* __restrict__ bdu,
                                                   const float* __restrict__ bdd,
                                                   float* __restrict__ outp) {
    __shared__ float z[KK];
    __shared__ int fidx[KK];
    int b = blockIdx.x, tid = threadIdx.x;
    int which = b >> 10, t = b & 1023;
    const float* vals = which ? vals_dn : vals_up;
    const int* idxs = which ? idx_dn : idx_up;
    const u16* WdT = which ? WddT16 : WduT16;
    const float* bd = which ? bdd : bdu;
    float* o = outp + (size_t)which * NTOK * DIM + (size_t)t * DIM;
    if (tid < KK) { z[tid] = vals[(size_t)t * KK + tid]; fidx[tid] = idxs[(size_t)t * KK + tid]; }
    __syncthreads();
    float a0 = 0.f, a1 = 0.f, a2 = 0.f;
    for (int j = 0; j < KK; ++j) {
        const u16* wr = WdT + (size_t)fidx[j] * DIM;
        float zj = z[j];
        a0 = fmaf(zj, bf2f(wr[tid]), a0);
        a1 = fmaf(zj, bf2f(wr[tid + 256]), a1);
        a2 = fmaf(zj, bf2f(wr[tid + 512]), a2);
    }
    o[tid]       = a0 + bd[tid];
    o[tid + 256] = a1 + bd[tid + 256];
    o[tid + 512] = a2 + bd[tid + 512];
}

extern "C" void kernel_launch(void* const* d_in, const int* in_sizes, int n_in,
                              void* d_out, int out_size, void* d_ws, size_t ws_size,
                              hipStream_t stream) {
    const float* x0  = (const float*)d_in[0];
    const float* xu  = (const float*)d_in[1];
    const float* ln  = (const float*)d_in[2];
    const float* Weu = (const float*)d_in[3];
    const float* beu = (const float*)d_in[4];
    const float* Wdu = (const float*)d_in[5];
    const float* bdu = (const float*)d_in[6];
    const float* Wed = (const float*)d_in[7];
    const float* bed = (const float*)d_in[8];
    const float* Wdd = (const float*)d_in[9];
    const float* bdd = (const float*)d_in[10];
    const int* conn = (const int*)d_in[11];
    float* out = (float*)d_out;

    // workspace carve-up (~62.7 MiB)
    char* w = (char*)d_ws;
    size_t off = 0;
    auto take = [&](size_t bytes) { char* p = w + off; off = (off + bytes + 255) & ~(size_t)255; return p; };
    u16*   X16     = (u16*)take((size_t)NTOK * FF * 2);        // 16 MiB
    u16*   B16     = (u16*)take((size_t)FF * DIM * 2);         // 12.6 MiB (Weu16/Wed16)
    u16*   WddT16  = X16;                                      // alias: after phase2sel
    u16*   WduT16  = B16;                                      // alias: after vconn
    float* WduT    = (float*)take((size_t)FF * DIM * 4);       // 25.2 MiB (f32, exact)
    u16*   A16     = (u16*)take((size_t)NTOK * DIM * 2);       // 1.5 MiB (shared up/down)
    u16*   inv_fd  = (u16*)take((size_t)FF * CC * 2);          // 2 MiB
    u16*   cclean  = (u16*)take((size_t)FF * CC * 2);          // 2 MiB
    u32*   pe      = (u32*)take((size_t)FF * CC * 4);          // 4 MiB packed entries
    u16*   cand_u  = (u16*)take((size_t)NTOK * CAP * 2);
    u16*   cand_d  = (u16*)take((size_t)NTOK * CAP * 2);
    int*   cnt_u   = (int*)take(NTOK * 4);
    int*   cnt_d   = (int*)take(NTOK * 4);
    float* vals_up = (float*)take((size_t)NTOK * KK * 4);
    int*   idx_up  = (int*)take((size_t)NTOK * KK * 4);
    float* vals_dn = (float*)take((size_t)NTOK * KK * 4);
    int*   idx_dn  = (int*)take((size_t)NTOK * KK * 4);
    float* sF      = (float*)take(FF * 4);
    float* tuF     = (float*)take(FF * 4);
    float* c2F     = (float*)take(FF * 4);
    double* s64    = (double*)take(FF * 8);
    double* tu64   = (double*)take(FF * 8);
    double* td64   = (double*)take(FF * 8);
    u32*   deg     = (u32*)take(FF * 4);
    u32*   cursor  = (u32*)take(FF * 4);
    u32*   offs    = (u32*)take((FF + 8) * 4);

    dim3 tgrid(FF / 32, DIM / 32), tblk(32, 8);
    dim3 ggrid(FF / 128, NTOK / 128);
    int nA4 = NTOK * DIM / 4, nB4 = FF * DIM / 4;

    // prep
    transpose_kernel<<<tgrid, tblk, 0, stream>>>(Wdu, WduT);
    bias_kernel<<<FF, 64, 0, stream>>>(Weu, Wed, bdu, bdd, bed, sF, tuF, c2F,
                                       s64, tu64, td64);
    hipMemsetAsync(deg, 0, 2 * FF * sizeof(u32), stream);  // deg + cursor (adjacent)
    dedup_deg_kernel<<<FF, CC, 0, stream>>>(conn, deg);
    scan_kernel<<<1, 256, 0, stream>>>(deg, offs);
    fill_kernel<<<FF, CC, 0, stream>>>(conn, offs, cursor, inv_fd, cclean);

    // upstream
    convert_kernel<<<(nA4 + 255) / 256, 256, 0, stream>>>(xu, A16, nA4);
    convert_kernel<<<(nB4 + 255) / 256, 256, 0, stream>>>(Weu, B16, nB4);
    gemm_mfma<0><<<ggrid, 256, 0, stream>>>(A16, B16, X16, sF, beu);
    select_up_kernel<<<NTOK, 256, 0, stream>>>(X16, cand_u, cnt_u);
    fixup_up<<<NTOK, 512, 0, stream>>>(xu, Weu, s64, beu, cand_u, cnt_u, vals_up, idx_up);

    // downstream
    convert_kernel<<<(nA4 + 255) / 256, 256, 0, stream>>>(x0, A16, nA4);
    convert_kernel<<<(nB4 + 255) / 256, 256, 0, stream>>>(Wed, B16, nB4);
    gemm_mfma<1><<<ggrid, 256, 0, stream>>>(A16, B16, X16, sF, beu);
    vconn_chunk<<<FF, 256, 0, stream>>>(B16, WduT, offs, inv_fd, pe, 0, 1);
    vconn_chunk<<<FF, 256, 0, stream>>>(B16, WduT, offs, inv_fd, pe, 1, 0);
    vconn_chunk<<<FF, 256, 0, stream>>>(B16, WduT, offs, inv_fd, pe, 2, 0);
    vconn_chunk<<<FF, 256, 0, stream>>>(B16, WduT, offs, inv_fd, pe, 3, 0);
    // B16 dead -> build bf16 decode weights for upstream (straight convert of WduT)
    convert_kernel<<<(nB4 + 255) / 256, 256, 0, stream>>>(WduT, WduT16, nB4);
    phase2sel<<<NTOK, 256, 0, stream>>>(X16, vals_up, idx_up, offs, pe,
                                        tuF, c2F, ln, cand_d, cnt_d);
    fixup_dn<<<NTOK, 512, 0, stream>>>(x0, Wed, WduT, tu64, td64, bed, ln, cclean,
                                       vals_up, idx_up, cand_d, cnt_d, vals_dn, idx_dn);

    // X16 dead -> bf16 transpose of Wdd, then both decodes
    transpose16_kernel<<<tgrid, tblk, 0, stream>>>(Wdd, WddT16);
    decode_both<<<2 * NTOK, 256, 0, stream>>>(vals_up, idx_up, vals_dn, idx_dn,
                                              WduT16, WddT16, bdu, bdd, out);
}

// Round 9
// 774.287 us; speedup vs baseline: 1.1374x; 1.0092x over previous
//
#include <hip/hip_runtime.h>

// SCAESuite R9: float4 gather rows in fixups, KSEL_DN 80, 512-thr selects,
// f32-direct GEMM staging (in-register bf16 pack).
// n=1024 tokens, D=768, F=8192, K=64, C=128. Inputs f32, output f32.
//  - gemm_mfma: reads f32 A/B, packs bf16 in-register -> LDS -> 16x16x32 MFMA
//  - vconn: 4 D-chunk launches (3MB gather set, L2-resident), packed pe entries
//  - phase2sel/select_up: 512 threads, in-place u16 keys, parallel radix
//  - fixup_*: 512 threads, float4 row gathers, exact f64 rescore, bitonic top-64
//  - decode_both: bf16 weight rows
//  - ws ~61 MiB; WduT16 aliases B16, WddT16 aliases X16

#define NTOK 1024
#define DIM  768
#define FF   8192
#define KK   64
#define CC   128
#define KSEL_UP 80
#define KSEL_DN 80
#define CAP  128

typedef unsigned short u16;
typedef unsigned int   u32;
typedef __attribute__((ext_vector_type(8))) short short8;
typedef __attribute__((ext_vector_type(4))) float floatx4;

__device__ __forceinline__ float bits2f(u32 v) {
    float f; __builtin_memcpy(&f, &v, 4); return f;
}
__device__ __forceinline__ float bf2f(u16 u) { return bits2f(((u32)u) << 16); }
__device__ __forceinline__ u16 f2bf(float f) {
    u32 u; __builtin_memcpy(&u, &f, 4);
    u32 lsb = (u >> 16) & 1u;
    u += 0x7fffu + lsb;
    return (u16)(u >> 16);
}
__device__ __forceinline__ u16 bfkey(u16 b) {
    return (b & 0x8000u) ? (u16)~b : (u16)(b | 0x8000u);
}
__device__ __forceinline__ int4 pack8(float4 a, float4 b) {
    int4 r;
    r.x = (int)((u32)f2bf(a.x) | ((u32)f2bf(a.y) << 16));
    r.y = (int)((u32)f2bf(a.z) | ((u32)f2bf(a.w) << 16));
    r.z = (int)((u32)f2bf(b.x) | ((u32)f2bf(b.y) << 16));
    r.w = (int)((u32)f2bf(b.z) | ((u32)f2bf(b.w) << 16));
    return r;
}

// ---------------- f32 -> bf16 bulk convert --------------------------------------
__global__ __launch_bounds__(256) void convert_kernel(const float* __restrict__ src,
                                                      u16* __restrict__ dst, int n4) {
    int i = blockIdx.x * 256 + threadIdx.x;
    if (i < n4) {
        float4 v = ((const float4*)src)[i];
        ushort4 o;
        o.x = f2bf(v.x); o.y = f2bf(v.y); o.z = f2bf(v.z); o.w = f2bf(v.w);
        ((ushort4*)dst)[i] = o;
    }
}

// ---------------- transpose: f32 [DIM][FF] -> f32 [FF][DIM] ---------------------
__global__ __launch_bounds__(256) void transpose_kernel(const float* __restrict__ in,
                                                        float* __restrict__ out) {
    __shared__ float tile[32][33];
    int f0 = blockIdx.x * 32, d0 = blockIdx.y * 32;
    int tx = threadIdx.x, ty = threadIdx.y;
#pragma unroll
    for (int i = 0; i < 4; ++i)
        tile[ty + 8 * i][tx] = in[(size_t)(d0 + ty + 8 * i) * FF + f0 + tx];
    __syncthreads();
#pragma unroll
    for (int i = 0; i < 4; ++i)
        out[(size_t)(f0 + ty + 8 * i) * DIM + d0 + tx] = tile[tx][ty + 8 * i];
}

// ---------------- transpose: f32 [DIM][FF] -> bf16 [FF][DIM] --------------------
__global__ __launch_bounds__(256) void transpose16_kernel(const float* __restrict__ in,
                                                          u16* __restrict__ out) {
    __shared__ float tile[32][33];
    int f0 = blockIdx.x * 32, d0 = blockIdx.y * 32;
    int tx = threadIdx.x, ty = threadIdx.y;
#pragma unroll
    for (int i = 0; i < 4; ++i)
        tile[ty + 8 * i][tx] = in[(size_t)(d0 + ty + 8 * i) * FF + f0 + tx];
    __syncthreads();
#pragma unroll
    for (int i = 0; i < 4; ++i)
        out[(size_t)(f0 + ty + 8 * i) * DIM + d0 + tx] = f2bf(tile[tx][ty + 8 * i]);
}

// ---------------- bias dots (f32 + f64 copies + c2 = bed - t_dn) ----------------
__global__ __launch_bounds__(64) void bias_kernel(const float* __restrict__ Weu,
                                                  const float* __restrict__ Wed,
                                                  const float* __restrict__ bdu,
                                                  const float* __restrict__ bdd,
                                                  const float* __restrict__ bed,
                                                  float* __restrict__ sF,
                                                  float* __restrict__ tuF,
                                                  float* __restrict__ c2F,
                                                  double* __restrict__ s64,
                                                  double* __restrict__ tu64,
                                                  double* __restrict__ td64) {
    int f = blockIdx.x, lane = threadIdx.x;
    double su = 0.0, tu = 0.0, td = 0.0;
    for (int i = lane; i < DIM; i += 64) {
        double bu = (double)bdu[i], bd = (double)bdd[i];
        su += (double)Weu[(size_t)f * DIM + i] * bu;
        double w = (double)Wed[(size_t)f * DIM + i];
        tu += w * bu;
        td += w * bd;
    }
#pragma unroll
    for (int off = 32; off; off >>= 1) {
        su += __shfl_xor(su, off);
        tu += __shfl_xor(tu, off);
        td += __shfl_xor(td, off);
    }
    if (lane == 0) {
        sF[f] = (float)su; tuF[f] = (float)tu;
        c2F[f] = (float)((double)bed[f] - td);
        s64[f] = su; tu64[f] = tu; td64[f] = td;
    }
}

// ---------------- bf16 MFMA GEMM from f32 inputs --------------------------------
template <int MODE>
__global__ __launch_bounds__(256) void gemm_mfma(const float* __restrict__ Af,
                                                 const float* __restrict__ Bf,
                                                 u16* __restrict__ Xout,
                                                 const float* __restrict__ sF,
                                                 const float* __restrict__ b_enc) {
    __shared__ __align__(16) u16 As[128 * 40];
    __shared__ __align__(16) u16 Bs[128 * 40];
    int tid = threadIdx.x;
    int wave = tid >> 6, lane = tid & 63;
    int lm = lane & 15, quad = lane >> 4;
    int m0 = blockIdx.y * 128, n0 = blockIdx.x * 128;
    int wm = (wave >> 1) * 64, wn = (wave & 1) * 64;
    floatx4 acc[4][4];
#pragma unroll
    for (int i = 0; i < 4; ++i)
#pragma unroll
        for (int j = 0; j < 4; ++j)
            acc[i][j] = (floatx4){0.f, 0.f, 0.f, 0.f};
    int r = tid >> 2;
    int s = (tid & 3) * 8;
    const float* gA = Af + (size_t)(m0 + r) * DIM + s;
    const float* gB = Bf + (size_t)(n0 + r) * DIM + s;
    for (int k0 = 0; k0 < DIM; k0 += 32) {
        float4 a0 = *(const float4*)(gA + k0);
        float4 a1 = *(const float4*)(gA + k0 + 4);
        float4 a2 = *(const float4*)(gA + (size_t)64 * DIM + k0);
        float4 a3 = *(const float4*)(gA + (size_t)64 * DIM + k0 + 4);
        float4 b0 = *(const float4*)(gB + k0);
        float4 b1 = *(const float4*)(gB + k0 + 4);
        float4 b2 = *(const float4*)(gB + (size_t)64 * DIM + k0);
        float4 b3 = *(const float4*)(gB + (size_t)64 * DIM + k0 + 4);
        __syncthreads();
        *(int4*)&As[r * 40 + s]        = pack8(a0, a1);
        *(int4*)&As[(r + 64) * 40 + s] = pack8(a2, a3);
        *(int4*)&Bs[r * 40 + s]        = pack8(b0, b1);
        *(int4*)&Bs[(r + 64) * 40 + s] = pack8(b2, b3);
        __syncthreads();
        short8 af[4], bfr[4];
#pragma unroll
        for (int mi = 0; mi < 4; ++mi)
            af[mi] = *(const short8*)&As[(wm + mi * 16 + lm) * 40 + quad * 8];
#pragma unroll
        for (int ni = 0; ni < 4; ++ni)
            bfr[ni] = *(const short8*)&Bs[(wn + ni * 16 + lm) * 40 + quad * 8];
#pragma unroll
        for (int mi = 0; mi < 4; ++mi)
#pragma unroll
            for (int ni = 0; ni < 4; ++ni)
                acc[mi][ni] = __builtin_amdgcn_mfma_f32_16x16x32_bf16(
                    af[mi], bfr[ni], acc[mi][ni], 0, 0, 0);
    }
#pragma unroll
    for (int ni = 0; ni < 4; ++ni) {
        int col = n0 + wn + ni * 16 + lm;
        float sub = 0.f, bb = 0.f;
        if (MODE == 0) { sub = sF[col]; bb = b_enc[col]; }
#pragma unroll
        for (int mi = 0; mi < 4; ++mi) {
#pragma unroll
            for (int reg = 0; reg < 4; ++reg) {
                int row = m0 + wm + mi * 16 + quad * 4 + reg;
                float v = acc[mi][ni][reg];
                if (MODE == 0) { v = v - sub + bb; v = v > 0.f ? v : 0.f; }
                Xout[(size_t)row * FF + col] = f2bf(v);
            }
        }
    }
}

// ---------------- parallel threshold find: suffix scan over hist[256] -----------
__device__ void find_threshold(u32* hist, int k, u32* sc) {
    int tid = threadIdx.x;
    for (int st = 1; st < 256; st <<= 1) {
        u32 v = 0;
        if (tid < 256) {
            v = hist[tid];
            if (tid + st < 256) v += hist[tid + st];
        }
        __syncthreads();
        if (tid < 256) hist[tid] = v;
        __syncthreads();
    }
    if (tid < 256) {
        u32 ge = hist[tid];
        u32 gn = (tid < 255) ? hist[tid + 1] : 0u;
        if ((int)ge >= k && (int)gn < k) { sc[0] = (u32)tid; sc[1] = (u32)(k - (int)gn); }
    }
    __syncthreads();
}

// ---------------- 2-pass u16 radix collect (any block size) ---------------------
template <typename KT>
__device__ void radix_collect(const KT* __restrict__ keys, u32* hist, int* eqidx,
                              u32* sc, int ksel, u16* cr, int* cnt_out, int row) {
    int tid = threadIdx.x, bs = blockDim.x;
    if (tid < 256) hist[tid] = 0;
    __syncthreads();
    for (int i = tid; i < FF; i += bs) atomicAdd(&hist[((u32)keys[i] & 0xffffu) >> 8], 1u);
    __syncthreads();
    find_threshold(hist, ksel, sc);
    int hb = (int)sc[0], k1 = (int)sc[1];
    if (tid < 256) hist[tid] = 0;
    __syncthreads();
    for (int i = tid; i < FF; i += bs) {
        u32 k = (u32)keys[i] & 0xffffu;
        if ((int)(k >> 8) == hb) atomicAdd(&hist[k & 255u], 1u);
    }
    __syncthreads();
    find_threshold(hist, k1, sc);
    u32 T = ((u32)hb << 8) | sc[0];
    if (tid == 0) { sc[2] = 0; sc[3] = 0; }
    __syncthreads();
    for (int i = tid; i < FF; i += bs) {
        u32 k = (u32)keys[i] & 0xffffu;
        if (k > T) {
            u32 p = atomicAdd(&sc[2], 1u);
            if (p < CAP) cr[p] = (u16)i;
        } else if (k == T) {
            u32 p = atomicAdd(&sc[3], 1u);
            if (p < 256) eqidx[p] = i;
        }
    }
    __syncthreads();
    if (tid == 0) {
        int G = (int)sc[2]; if (G > CAP) G = CAP;
        int ne = (int)sc[3]; if (ne > 256) ne = 256;
        int total = G;
        for (int q = 0; q < ne && total < CAP; ++q) cr[total++] = (u16)eqidx[q];
        cnt_out[row] = total;
    }
}

// ---------------- select_up: 512 threads, u16 keys in LDS -----------------------
__global__ __launch_bounds__(512) void select_up_kernel(const u16* __restrict__ X16,
                                                        u16* __restrict__ cand,
                                                        int* __restrict__ cnt) {
    __shared__ u16 keys[FF];
    __shared__ u32 hist[256];
    __shared__ int eqidx[256];
    __shared__ u32 sc[4];
    const int row = blockIdx.x, tid = threadIdx.x;
    const ushort4* src = (const ushort4*)(X16 + (size_t)row * FF);
    for (int i = tid; i < FF / 4; i += 512) {
        ushort4 u = src[i];
        keys[i * 4]     = bfkey(u.x);
        keys[i * 4 + 1] = bfkey(u.y);
        keys[i * 4 + 2] = bfkey(u.z);
        keys[i * 4 + 3] = bfkey(u.w);
    }
    __syncthreads();
    radix_collect<u16>(keys, hist, eqidx, sc, KSEL_UP, cand + (size_t)row * CAP, cnt, row);
}

// ---------------- bitonic sort of 128 (desc by val, asc idx) --------------------
__device__ __forceinline__ bool sort_before(double av, int ai, double bv, int bi) {
    return (av > bv) || (av == bv && ai < bi);
}
__device__ void bitonic128(double* sv, int* si, int tid) {
    for (int k = 2; k <= 128; k <<= 1) {
        for (int j = k >> 1; j > 0; j >>= 1) {
            __syncthreads();
            if (tid < 64) {
                int i = ((tid & ~(j - 1)) << 1) | (tid & (j - 1));
                int l = i, rr = i + j;
                bool bfirst = sort_before(sv[rr], si[rr], sv[l], si[l]);
                bool doswap = ((i & k) == 0) ? bfirst : !bfirst;
                if (doswap) {
                    double tv = sv[l]; sv[l] = sv[rr]; sv[rr] = tv;
                    int ti = si[l]; si[l] = si[rr]; si[rr] = ti;
                }
            }
        }
    }
    __syncthreads();
}

// ---------------- exact rescore (up), 512 threads, float4 rows ------------------
__global__ __launch_bounds__(512) void fixup_up(const float* __restrict__ xu,
                                                const float* __restrict__ Weu,
                                                const double* __restrict__ s64,
                                                const float* __restrict__ beu,
                                                const u16* __restrict__ cand,
                                                const int* __restrict__ cnt,
                                                float* __restrict__ vals,
                                                int* __restrict__ idxs) {
    __shared__ float xrow[DIM];
    __shared__ double sv[128];
    __shared__ int si[128];
    int t = blockIdx.x, tid = threadIdx.x, wave = tid >> 6, lane = tid & 63;
    for (int i = tid; i < DIM; i += 512) xrow[i] = xu[(size_t)t * DIM + i];
    for (int c = tid; c < 128; c += 512) { sv[c] = -1.0e300; si[c] = 0x7fffffff; }
    __syncthreads();
    int nc = cnt[t]; if (nc > 128) nc = 128;
    const float4* xr4 = (const float4*)xrow;
    for (int c = wave; c < nc; c += 8) {
        int f = (int)cand[(size_t)t * CAP + c];
        const float4* wr4 = (const float4*)(Weu + (size_t)f * DIM);
        float4 w0 = wr4[lane], w1 = wr4[lane + 64], w2 = wr4[lane + 128];
        float4 x0 = xr4[lane], x1 = xr4[lane + 64], x2 = xr4[lane + 128];
        double p = (double)x0.x * w0.x + (double)x0.y * w0.y
                 + (double)x0.z * w0.z + (double)x0.w * w0.w;
        p += (double)x1.x * w1.x + (double)x1.y * w1.y
           + (double)x1.z * w1.z + (double)x1.w * w1.w;
        p += (double)x2.x * w2.x + (double)x2.y * w2.y
           + (double)x2.z * w2.z + (double)x2.w * w2.w;
#pragma unroll
        for (int off = 32; off; off >>= 1) p += __shfl_xor(p, off);
        if (lane == 0) {
            double v = p - s64[f] + (double)beu[f];
            v = v > 0.0 ? v : 0.0;
            sv[c] = v; si[c] = f;
        }
    }
    __syncthreads();
    bitonic128(sv, si, tid);
    if (tid < KK) {
        vals[(size_t)t * KK + tid] = (float)sv[tid];
        idxs[(size_t)t * KK + tid] = si[tid];
    }
}

// ---------------- exact rescore (down), 512 threads, float4 rows ----------------
__global__ __launch_bounds__(512) void fixup_dn(const float* __restrict__ x0g,
                                                const float* __restrict__ Wed,
                                                const float* __restrict__ WduT,
                                                const double* __restrict__ tu64,
                                                const double* __restrict__ td64,
                                                const float* __restrict__ bed,
                                                const float* __restrict__ ln,
                                                const u16* __restrict__ cclean,
                                                const float* __restrict__ vals_up,
                                                const int* __restrict__ idx_up,
                                                const u16* __restrict__ cand,
                                                const int* __restrict__ cnt,
                                                float* __restrict__ vals,
                                                int* __restrict__ idxs) {
    __shared__ float xrow[DIM];
    __shared__ u32 bm[256];
    __shared__ int fl[KK];
    __shared__ float zl[KK];
    __shared__ double sv[128];
    __shared__ int si[128];
    int t = blockIdx.x, tid = threadIdx.x, wave = tid >> 6, lane = tid & 63;
    for (int i = tid; i < DIM; i += 512) xrow[i] = x0g[(size_t)t * DIM + i];
    if (tid < 256) bm[tid] = 0;
    for (int c = tid; c < 128; c += 512) { sv[c] = -1.0e300; si[c] = 0x7fffffff; }
    __syncthreads();
    if (tid < KK) {
        int f = idx_up[(size_t)t * KK + tid];
        fl[tid] = f; zl[tid] = vals_up[(size_t)t * KK + tid];
        atomicOr(&bm[f >> 5], 1u << (f & 31));
    }
    __syncthreads();
    int nc = cnt[t]; if (nc > 128) nc = 128;
    double lnt = (double)ln[t];
    const float4* xr4 = (const float4*)xrow;
    for (int c = wave; c < nc; c += 8) {
        int f = (int)cand[(size_t)t * CAP + c];
        const float4* wr4 = (const float4*)(Wed + (size_t)f * DIM);
        const u16* crow = cclean + (size_t)f * CC;
        int e0 = (int)crow[lane], e1 = (int)crow[lane + 64];
        float4 w0 = wr4[lane], w1 = wr4[lane + 64], w2 = wr4[lane + 128];
        float4 x0 = xr4[lane], x1 = xr4[lane + 64], x2 = xr4[lane + 128];
        double p = (double)x0.x * w0.x + (double)x0.y * w0.y
                 + (double)x0.z * w0.z + (double)x0.w * w0.w;
        p += (double)x1.x * w1.x + (double)x1.y * w1.y
           + (double)x1.z * w1.z + (double)x1.w * w1.w;
        p += (double)x2.x * w2.x + (double)x2.y * w2.y
           + (double)x2.z * w2.z + (double)x2.w * w2.w;
        bool h0 = (e0 != 0xFFFF) && ((bm[e0 >> 5] >> (e0 & 31)) & 1u);
        bool h1 = (e1 != 0xFFFF) && ((bm[e1 >> 5] >> (e1 & 31)) & 1u);
        unsigned long long m0 = __ballot(h0), m1 = __ballot(h1);
        while (m0 | m1) {
            int fu;
            if (m0) {
                int b = __ffsll((long long)m0) - 1; m0 &= m0 - 1;
                fu = __shfl(e0, b);
            } else {
                int b = __ffsll((long long)m1) - 1; m1 &= m1 - 1;
                fu = __shfl(e1, b);
            }
            unsigned long long zm = __ballot(fl[lane] == fu);
            float z = zl[__ffsll((long long)zm) - 1];
            const float4* du4 = (const float4*)(WduT + (size_t)fu * DIM);
            float4 d0 = du4[lane], d1 = du4[lane + 64], d2 = du4[lane + 128];
            double vp = (double)w0.x * d0.x + (double)w0.y * d0.y
                      + (double)w0.z * d0.z + (double)w0.w * d0.w;
            vp += (double)w1.x * d1.x + (double)w1.y * d1.y
                + (double)w1.z * d1.z + (double)w1.w * d1.w;
            vp += (double)w2.x * d2.x + (double)w2.y * d2.y
                + (double)w2.z * d2.z + (double)w2.w * d2.w;
            p += (double)z * vp;
        }
#pragma unroll
        for (int off = 32; off; off >>= 1) p += __shfl_xor(p, off);
        if (lane == 0) {
            double v = (p + tu64[f]) / lnt + (double)bed[f] - td64[f];
            sv[c] = v; si[c] = f;
        }
    }
    __syncthreads();
    bitonic128(sv, si, tid);
    if (tid < KK) {
        vals[(size_t)t * KK + tid] = (float)sv[tid];
        idxs[(size_t)t * KK + tid] = si[tid];
    }
}

// ---------------- conn dedupe + inverse-index build -----------------------------
__global__ __launch_bounds__(128) void dedup_deg_kernel(const int* __restrict__ conn,
                                                        u32* __restrict__ deg) {
    __shared__ int row[CC];
    int fd = blockIdx.x, c = threadIdx.x;
    int v = conn[(size_t)fd * CC + c];
    row[c] = v;
    __syncthreads();
    bool dup = false;
    for (int j = 0; j < c; ++j) dup |= (row[j] == v);
    if (!dup) atomicAdd(&deg[v], 1u);
}

__global__ __launch_bounds__(256) void scan_kernel(const u32* __restrict__ deg,
                                                   u32* __restrict__ offs) {
    __shared__ u32 sdeg[FF];
    __shared__ u32 part[256];
    int tid = threadIdx.x;
    for (int i = tid; i < FF; i += 256) sdeg[i] = deg[i];
    __syncthreads();
    u32 s = 0;
    for (int j = 0; j < 32; ++j) s += sdeg[tid * 32 + j];
    part[tid] = s;
    __syncthreads();
    if (tid == 0) {
        u32 run = 0;
        for (int i = 0; i < 256; ++i) { u32 v = part[i]; part[i] = run; run += v; }
        offs[FF] = run;
    }
    __syncthreads();
    u32 run = part[tid];
    for (int j = 0; j < 32; ++j) { offs[tid * 32 + j] = run; run += sdeg[tid * 32 + j]; }
}

__global__ __launch_bounds__(128) void fill_kernel(const int* __restrict__ conn,
                                                   const u32* __restrict__ offs,
                                                   u32* __restrict__ cursor,
                                                   u16* __restrict__ inv_fd,
                                                   u16* __restrict__ cclean) {
    __shared__ int row[CC];
    int fd = blockIdx.x, c = threadIdx.x;
    int v = conn[(size_t)fd * CC + c];
    row[c] = v;
    __syncthreads();
    bool dup = false;
    for (int j = 0; j < c; ++j) dup |= (row[j] == v);
    cclean[(size_t)fd * CC + c] = dup ? (u16)0xFFFF : (u16)v;
    if (!dup) {
        u32 slot = atomicAdd(&cursor[v], 1u);
        inv_fd[offs[v] + slot] = (u16)fd;
    }
}

// ---------------- vconn chunk -> packed pe[p] = (fd<<16)|bf16(partial) ----------
__global__ __launch_bounds__(256) void vconn_chunk(const u16* __restrict__ Wed16,
                                                   const float* __restrict__ WduT,
                                                   const u32* __restrict__ offs,
                                                   const u16* __restrict__ inv_fd,
                                                   u32* __restrict__ pe,
                                                   int chunk, int first) {
    __shared__ float row[192];
    int fu = blockIdx.x, tid = threadIdx.x;
    if (tid < 192) row[tid] = WduT[(size_t)fu * DIM + chunk * 192 + tid];
    __syncthreads();
    u32 s = offs[fu], e = offs[fu + 1];
    int wave = tid >> 6, lane = tid & 63;
    int sub = lane >> 4, sl = lane & 15;
    for (u32 p0 = s + (u32)wave * 4; p0 < e; p0 += 16) {
        u32 p = p0 + (u32)sub;
        bool valid = p < e;
        float a = 0.f;
        int fd = 0;
        u32 old = 0;
        if (valid) {
            if (first) fd = (int)inv_fd[p];
            else { old = pe[p]; fd = (int)(old >> 16); }
            const u16* wr = Wed16 + (size_t)fd * DIM + chunk * 192;
#pragma unroll
            for (int i = 0; i < 12; ++i)
                a = fmaf(bf2f(wr[sl + 16 * i]), row[sl + 16 * i], a);
        }
        a += __shfl_xor(a, 1);
        a += __shfl_xor(a, 2);
        a += __shfl_xor(a, 4);
        a += __shfl_xor(a, 8);
        if (valid && sl == 0) {
            float v = first ? a : (bf2f((u16)(old & 0xffffu)) + a);
            pe[p] = ((u32)fd << 16) | (u32)f2bf(v);
        }
    }
}

// ---------------- phase2 + select_dn fused: 512 threads, in-place keys ----------
__global__ __launch_bounds__(512) void phase2sel(const u16* __restrict__ X16,
                                                 const float* __restrict__ vals_up,
                                                 const int* __restrict__ idx_up,
                                                 const u32* __restrict__ offs,
                                                 const u32* __restrict__ pe,
                                                 const float* __restrict__ tuF,
                                                 const float* __restrict__ c2F,
                                                 const float* __restrict__ ln,
                                                 u16* __restrict__ cand,
                                                 int* __restrict__ cnt) {
    __shared__ u32 accbits[FF];        // 32 KB: f32 acc, then u16 keys in place
    __shared__ float zl[KK];
    __shared__ u32 offs_s[KK];
    __shared__ u32 ends_s[KK];
    __shared__ u32 hist[256];
    __shared__ int eqidx[256];
    __shared__ u32 sc[4];
    float* facc = (float*)accbits;
    int t = blockIdx.x, tid = threadIdx.x, wave = tid >> 6, lane = tid & 63;
    for (int i = tid; i < FF; i += 512) accbits[i] = 0u;
    if (tid < KK) {
        int f = idx_up[(size_t)t * KK + tid];
        zl[tid] = vals_up[(size_t)t * KK + tid];
        offs_s[tid] = offs[f];
        ends_s[tid] = offs[f + 1];
    }
    __syncthreads();
    // wave-per-segment scatter: 8 segments in flight, 3 loads pre-issued/lane
    for (int j = wave; j < KK; j += 8) {
        u32 s = offs_s[j], e = ends_s[j];
        float zj = zl[j];
        u32 p = s + (u32)lane;
        u32 v0 = 0, v1 = 0, v2 = 0;
        bool h0 = p < e, h1 = p + 64 < e, h2 = p + 128 < e;
        if (h0) v0 = pe[p];
        if (h1) v1 = pe[p + 64];
        if (h2) v2 = pe[p + 128];
        if (h0) atomicAdd(&facc[v0 >> 16], zj * bf2f((u16)(v0 & 0xffffu)));
        if (h1) atomicAdd(&facc[v1 >> 16], zj * bf2f((u16)(v1 & 0xffffu)));
        if (h2) atomicAdd(&facc[v2 >> 16], zj * bf2f((u16)(v2 & 0xffffu)));
        for (u32 q = p + 192; q < e; q += 64) {
            u32 v = pe[q];
            atomicAdd(&facc[v >> 16], zj * bf2f((u16)(v & 0xffffu)));
        }
    }
    __syncthreads();
    // epilogue + in-place key conversion (each index owned by one thread)
    float lnv = ln[t];
    const ushort4* xs = (const ushort4*)(X16 + (size_t)t * FF);
    const float4* tu4 = (const float4*)tuF;
    const float4* c24 = (const float4*)c2F;
    for (int i = tid; i < FF / 4; i += 512) {
        ushort4 u = xs[i];
        float4 tu = tu4[i], c2 = c24[i];
        int i4 = i * 4;
        float a0 = facc[i4], a1 = facc[i4 + 1], a2 = facc[i4 + 2], a3 = facc[i4 + 3];
        accbits[i4]     = (u32)bfkey(f2bf((bf2f(u.x) + a0 + tu.x) / lnv + c2.x));
        accbits[i4 + 1] = (u32)bfkey(f2bf((bf2f(u.y) + a1 + tu.y) / lnv + c2.y));
        accbits[i4 + 2] = (u32)bfkey(f2bf((bf2f(u.z) + a2 + tu.z) / lnv + c2.z));
        accbits[i4 + 3] = (u32)bfkey(f2bf((bf2f(u.w) + a3 + tu.w) / lnv + c2.w));
    }
    __syncthreads();
    radix_collect<u32>(accbits, hist, eqidx, sc, KSEL_DN, cand + (size_t)t * CAP, cnt, t);
}

// ---------------- both sparse decodes, bf16 weight rows -------------------------
__global__ __launch_bounds__(256) void decode_both(const float* __restrict__ vals_up,
                                                   const int* __restrict__ idx_up,
                                                   const float* __restrict__ vals_dn,
                                                   const int* __restrict__ idx_dn,
                                                   const u16* __restrict__ WduT16,
                                                   const u16* __restrict__ WddT16,
                                                   const float* __restrict__ bdu,
                                                   const float* __restrict__ bdd,
                                                   float* __restrict__ outp) {
    __shared__ float z[KK];
    __shared__ int fidx[KK];
    int b = blockIdx.x, tid = threadIdx.x;
    int which = b >> 10, t = b & 1023;
    const float* vals = which ? vals_dn : vals_up;
    const int* idxs = which ? idx_dn : idx_up;
    const u16* WdT = which ? WddT16 : WduT16;
    const float* bd = which ? bdd : bdu;
    float* o = outp + (size_t)which * NTOK * DIM + (size_t)t * DIM;
    if (tid < KK) { z[tid] = vals[(size_t)t * KK + tid]; fidx[tid] = idxs[(size_t)t * KK + tid]; }
    __syncthreads();
    float a0 = 0.f, a1 = 0.f, a2 = 0.f;
    for (int j = 0; j < KK; ++j) {
        const u16* wr = WdT + (size_t)fidx[j] * DIM;
        float zj = z[j];
        a0 = fmaf(zj, bf2f(wr[tid]), a0);
        a1 = fmaf(zj, bf2f(wr[tid + 256]), a1);
        a2 = fmaf(zj, bf2f(wr[tid + 512]), a2);
    }
    o[tid]       = a0 + bd[tid];
    o[tid + 256] = a1 + bd[tid + 256];
    o[tid + 512] = a2 + bd[tid + 512];
}

extern "C" void kernel_launch(void* const* d_in, const int* in_sizes, int n_in,
                              void* d_out, int out_size, void* d_ws, size_t ws_size,
                              hipStream_t stream) {
    const float* x0  = (const float*)d_in[0];
    const float* xu  = (const float*)d_in[1];
    const float* ln  = (const float*)d_in[2];
    const float* Weu = (const float*)d_in[3];
    const float* beu = (const float*)d_in[4];
    const float* Wdu = (const float*)d_in[5];
    const float* bdu = (const float*)d_in[6];
    const float* Wed = (const float*)d_in[7];
    const float* bed = (const float*)d_in[8];
    const float* Wdd = (const float*)d_in[9];
    const float* bdd = (const float*)d_in[10];
    const int* conn = (const int*)d_in[11];
    float* out = (float*)d_out;

    // workspace carve-up (~61 MiB)
    char* w = (char*)d_ws;
    size_t off = 0;
    auto take = [&](size_t bytes) { char* p = w + off; off = (off + bytes + 255) & ~(size_t)255; return p; };
    u16*   X16     = (u16*)take((size_t)NTOK * FF * 2);        // 16 MiB
    u16*   B16     = (u16*)take((size_t)FF * DIM * 2);         // 12.6 MiB (Wed16)
    u16*   WddT16  = X16;                                      // alias: after phase2sel
    u16*   WduT16  = B16;                                      // alias: after vconn
    float* WduT    = (float*)take((size_t)FF * DIM * 4);       // 25.2 MiB (f32, exact)
    u16*   inv_fd  = (u16*)take((size_t)FF * CC * 2);          // 2 MiB
    u16*   cclean  = (u16*)take((size_t)FF * CC * 2);          // 2 MiB
    u32*   pe      = (u32*)take((size_t)FF * CC * 4);          // 4 MiB packed entries
    u16*   cand_u  = (u16*)take((size_t)NTOK * CAP * 2);
    u16*   cand_d  = (u16*)take((size_t)NTOK * CAP * 2);
    int*   cnt_u   = (int*)take(NTOK * 4);
    int*   cnt_d   = (int*)take(NTOK * 4);
    float* vals_up = (float*)take((size_t)NTOK * KK * 4);
    int*   idx_up  = (int*)take((size_t)NTOK * KK * 4);
    float* vals_dn = (float*)take((size_t)NTOK * KK * 4);
    int*   idx_dn  = (int*)take((size_t)NTOK * KK * 4);
    float* sF      = (float*)take(FF * 4);
    float* tuF     = (float*)take(FF * 4);
    float* c2F     = (float*)take(FF * 4);
    double* s64    = (double*)take(FF * 8);
    double* tu64   = (double*)take(FF * 8);
    double* td64   = (double*)take(FF * 8);
    u32*   deg     = (u32*)take(FF * 4);
    u32*   cursor  = (u32*)take(FF * 4);
    u32*   offs    = (u32*)take((FF + 8) * 4);

    dim3 tgrid(FF / 32, DIM / 32), tblk(32, 8);
    dim3 ggrid(FF / 128, NTOK / 128);
    int nB4 = FF * DIM / 4;

    // prep
    transpose_kernel<<<tgrid, tblk, 0, stream>>>(Wdu, WduT);
    bias_kernel<<<FF, 64, 0, stream>>>(Weu, Wed, bdu, bdd, bed, sF, tuF, c2F,
                                       s64, tu64, td64);
    hipMemsetAsync(deg, 0, 2 * FF * sizeof(u32), stream);  // deg + cursor (adjacent)
    dedup_deg_kernel<<<FF, CC, 0, stream>>>(conn, deg);
    scan_kernel<<<1, 256, 0, stream>>>(deg, offs);
    fill_kernel<<<FF, CC, 0, stream>>>(conn, offs, cursor, inv_fd, cclean);

    // upstream (gemm reads f32 directly)
    gemm_mfma<0><<<ggrid, 256, 0, stream>>>(xu, Weu, X16, sF, beu);
    select_up_kernel<<<NTOK, 512, 0, stream>>>(X16, cand_u, cnt_u);
    fixup_up<<<NTOK, 512, 0, stream>>>(xu, Weu, s64, beu, cand_u, cnt_u, vals_up, idx_up);

    // downstream
    convert_kernel<<<(nB4 + 255) / 256, 256, 0, stream>>>(Wed, B16, nB4);
    gemm_mfma<1><<<ggrid, 256, 0, stream>>>(x0, Wed, X16, sF, beu);
    vconn_chunk<<<FF, 256, 0, stream>>>(B16, WduT, offs, inv_fd, pe, 0, 1);
    vconn_chunk<<<FF, 256, 0, stream>>>(B16, WduT, offs, inv_fd, pe, 1, 0);
    vconn_chunk<<<FF, 256, 0, stream>>>(B16, WduT, offs, inv_fd, pe, 2, 0);
    vconn_chunk<<<FF, 256, 0, stream>>>(B16, WduT, offs, inv_fd, pe, 3, 0);
    // B16 dead -> bf16 decode weights for upstream
    convert_kernel<<<(nB4 + 255) / 256, 256, 0, stream>>>(WduT, WduT16, nB4);
    phase2sel<<<NTOK, 512, 0, stream>>>(X16, vals_up, idx_up, offs, pe,
                                        tuF, c2F, ln, cand_d, cnt_d);
    fixup_dn<<<NTOK, 512, 0, stream>>>(x0, Wed, WduT, tu64, td64, bed, ln, cclean,
                                       vals_up, idx_up, cand_d, cnt_d, vals_dn, idx_dn);

    // X16 dead -> bf16 transpose of Wdd, then both decodes
    transpose16_kernel<<<tgrid, tblk, 0, stream>>>(Wdd, WddT16);
    decode_both<<<2 * NTOK, 256, 0, stream>>>(vals_up, idx_up, vals_dn, idx_dn,
                                              WduT16, WddT16, bdu, bdd, out);
}